// Round 1
// baseline (14207.146 us; speedup 1.0000x reference)
//
#include <hip/hip_runtime.h>
#include <hip/hip_cooperative_groups.h>
#include <math.h>

namespace cg = cooperative_groups;

// Problem constants
#define B 32
#define SENC 64
#define SDEC 32
#define HDIM 512
#define EDIM 512
#define VDIM 32000
#define G4 2048              // 4*H
#define BH (B*HDIM)          // 16384

// ---------------------------------------------------------------------------
// embed: gather emb rows for a token sequence  (n_tok blocks x 128 threads)
// ---------------------------------------------------------------------------
__global__ __launch_bounds__(128) void embed_kernel(const int* __restrict__ toks,
                                                    const float* __restrict__ emb,
                                                    float* __restrict__ out)
{
    int t = blockIdx.x;
    int id = toks[t];
    const float4* src = (const float4*)(emb + (size_t)id * EDIM);
    float4* dst = (float4*)(out + (size_t)t * EDIM);
    dst[threadIdx.x] = src[threadIdx.x];   // 128 * float4 = 512 floats
}

// ---------------------------------------------------------------------------
// Generic NT SGEMM: C[m,n] = sum_k A[m*K+k]*B[n*K+k] (+bias0[n]+bias1[n])
// block tile 128x64, 256 threads, 8x4 microtile.
// ---------------------------------------------------------------------------
__global__ __launch_bounds__(256) void gemm_nt(const float* __restrict__ A,
                                               const float* __restrict__ Bm,
                                               float* __restrict__ C,
                                               const float* __restrict__ bias0,
                                               const float* __restrict__ bias1,
                                               int M, int N, int K)
{
    __shared__ float As[16][128];
    __shared__ float Bs[16][64];
    int tid = threadIdx.x;
    int tx = tid & 15, ty = tid >> 4;
    int m0 = blockIdx.y * 128, n0 = blockIdx.x * 64;

    float acc[8][4];
    #pragma unroll
    for (int i = 0; i < 8; i++)
        #pragma unroll
        for (int j = 0; j < 4; j++) acc[i][j] = 0.f;

    int la_m = tid >> 1, la_k = (tid & 1) * 8;
    int lb_n = tid & 63, lb_k = (tid >> 6) * 4;
    const float* Aptr = A + (size_t)(m0 + la_m) * K + la_k;
    const float* Bptr = Bm + (size_t)(n0 + lb_n) * K + lb_k;

    for (int k0 = 0; k0 < K; k0 += 16) {
        float4 a1 = *(const float4*)(Aptr + k0);
        float4 a2 = *(const float4*)(Aptr + k0 + 4);
        float4 bv = *(const float4*)(Bptr + k0);
        As[la_k + 0][la_m] = a1.x; As[la_k + 1][la_m] = a1.y;
        As[la_k + 2][la_m] = a1.z; As[la_k + 3][la_m] = a1.w;
        As[la_k + 4][la_m] = a2.x; As[la_k + 5][la_m] = a2.y;
        As[la_k + 6][la_m] = a2.z; As[la_k + 7][la_m] = a2.w;
        Bs[lb_k + 0][lb_n] = bv.x; Bs[lb_k + 1][lb_n] = bv.y;
        Bs[lb_k + 2][lb_n] = bv.z; Bs[lb_k + 3][lb_n] = bv.w;
        __syncthreads();
        #pragma unroll
        for (int kk = 0; kk < 16; kk++) {
            float4 av1 = *(const float4*)&As[kk][ty * 8];
            float4 av2 = *(const float4*)&As[kk][ty * 8 + 4];
            float4 bvv = *(const float4*)&Bs[kk][tx * 4];
            float am[8] = {av1.x, av1.y, av1.z, av1.w, av2.x, av2.y, av2.z, av2.w};
            float bn[4] = {bvv.x, bvv.y, bvv.z, bvv.w};
            #pragma unroll
            for (int i = 0; i < 8; i++)
                #pragma unroll
                for (int j = 0; j < 4; j++)
                    acc[i][j] += am[i] * bn[j];
        }
        __syncthreads();
    }

    float bb[4] = {0.f, 0.f, 0.f, 0.f};
    int nc = n0 + tx * 4;
    if (bias0) {
        #pragma unroll
        for (int j = 0; j < 4; j++) bb[j] += bias0[nc + j];
    }
    if (bias1) {
        #pragma unroll
        for (int j = 0; j < 4; j++) bb[j] += bias1[nc + j];
    }
    #pragma unroll
    for (int i = 0; i < 8; i++) {
        int row = m0 + ty * 8 + i;
        float4 o = make_float4(acc[i][0] + bb[0], acc[i][1] + bb[1],
                               acc[i][2] + bb[2], acc[i][3] + bb[3]);
        *(float4*)(C + (size_t)row * N + nc) = o;
    }
}

// ---------------------------------------------------------------------------
// helpers
// ---------------------------------------------------------------------------
__device__ __forceinline__ float allreduce64(float v)
{
    #pragma unroll
    for (int m = 1; m < 64; m <<= 1) v += __shfl_xor(v, m);
    return v;
}

__device__ __forceinline__ float2 lstm_update(float i_, float f_, float g_,
                                              float o_, float c)
{
    float ig = 1.f / (1.f + expf(-i_));
    float fg = 1.f / (1.f + expf(-f_));
    float gg = tanhf(g_);
    float og = 1.f / (1.f + expf(-o_));
    float cn = fg * c + ig * gg;
    float hn = og * tanhf(cn);
    return make_float2(hn, cn);
}

// ---------------------------------------------------------------------------
// Persistent encoder layer: all 64 timesteps in one cooperative kernel.
// grid = 256 blocks = 64 jh-groups (8 jh) x 4 b-groups (8 b), 256 threads.
// thread (r,bb): r = gate-row-local (g*8+jj), bb = local batch.
// c state lives in registers of threads tid<64 (one per (jj,bb)).
// h exchanged via parity-double-buffered global hbuf + grid.sync per step.
// Whh read from global (row set per block is fixed -> XCD-L2-resident).
// ---------------------------------------------------------------------------
__global__ __launch_bounds__(256) void enc_layer_persist(
    const float* __restrict__ xg, const float* __restrict__ Whh,
    float* __restrict__ seq_out, float* __restrict__ hbuf,
    float* __restrict__ hT, float* __restrict__ cT)
{
    __shared__ __align__(16) float hs[8][520];   // pad 520: 2-way bank alias (free)
    __shared__ float gacc[8][8][4];              // [jj][bb][gate]
    cg::grid_group grid = cg::this_grid();
    int blk = blockIdx.x;
    int jg = blk >> 2, bg = blk & 3;
    int tid = threadIdx.x;
    int r = tid >> 3, bb = tid & 7;
    int g = r >> 3, jj = r & 7;
    int row = (g << 9) + (jg << 3) + jj;         // gate-row in [0,2048)
    int b = (bg << 3) + bb;
    const float* wrow = Whh + (size_t)row * 512;
    float creg = 0.f;
    int p = 0;
    for (int t = 0; t < SENC; ++t) {
        float accx = xg[(size_t)(b * SENC + t) * G4 + row];
        if (t == 0) {
            float4 z = make_float4(0.f, 0.f, 0.f, 0.f);
            for (int i = tid; i < 8 * 128; i += 256) {
                int rb = i >> 7, kk = (i & 127) << 2;
                *(float4*)&hs[rb][kk] = z;
            }
        } else {
            const float* src = hbuf + p * BH + ((bg << 3) << 9);
            for (int i = tid; i < 8 * 128; i += 256) {
                int rb = i >> 7, kk = (i & 127) << 2;
                *(float4*)&hs[rb][kk] = *(const float4*)(src + (rb << 9) + kk);
            }
        }
        __syncthreads();
        float a0 = 0.f, a1 = 0.f, a2 = 0.f, a3 = 0.f;
        const float* hr = hs[bb];
        #pragma unroll 8
        for (int k = 0; k < 512; k += 4) {
            float4 w = *(const float4*)(wrow + k);
            float4 h = *(const float4*)(hr + k);
            a0 += w.x * h.x; a1 += w.y * h.y;
            a2 += w.z * h.z; a3 += w.w * h.w;
        }
        gacc[jj][bb][g] = accx + (a0 + a1) + (a2 + a3);
        __syncthreads();
        if (tid < 64) {
            int ujj = tid >> 3, ubb = tid & 7;
            float2 hc = lstm_update(gacc[ujj][ubb][0], gacc[ujj][ubb][1],
                                    gacc[ujj][ubb][2], gacc[ujj][ubb][3], creg);
            creg = hc.y;
            int ub = (bg << 3) + ubb, ujh = (jg << 3) + ujj;
            hbuf[(p ^ 1) * BH + ub * 512 + ujh] = hc.x;
            seq_out[(size_t)(ub * SENC + t) * 512 + ujh] = hc.x;
            if (t == SENC - 1) {
                hT[ub * 512 + ujh] = hc.x;
                cT[ub * 512 + ujh] = hc.y;
            }
        }
        grid.sync();
        p ^= 1;
    }
}

// ---------------------------------------------------------------------------
// Decoder cell phase (device fn): g = bsum + Wih@inp + Whh@h, LSTM update.
// Same (jg,bg)/(r,bb) decomposition as the encoder. Weights from global L2.
// ---------------------------------------------------------------------------
__device__ __forceinline__ void cell_phase(
    const float* __restrict__ Wih, const float* __restrict__ Whh,
    float bsum,
    const float* __restrict__ inp, const float* __restrict__ h_in,
    float* __restrict__ h_out, float* __restrict__ seqout,
    float& creg, int t, int jg, int bg, int row,
    float (*hs)[520], float (*is_)[520], float (*gacc)[8][4])
{
    int tid = threadIdx.x;
    {
        const float* hsrc = h_in + ((bg << 3) << 9);
        const float* isrc = inp + ((bg << 3) << 9);
        for (int i = tid; i < 8 * 128; i += 256) {
            int rb = i >> 7, kk = (i & 127) << 2;
            *(float4*)&hs[rb][kk] = *(const float4*)(hsrc + (rb << 9) + kk);
            *(float4*)&is_[rb][kk] = *(const float4*)(isrc + (rb << 9) + kk);
        }
    }
    __syncthreads();
    int r = tid >> 3, bb = tid & 7;
    int g = r >> 3, jj = r & 7;
    const float* wi = Wih + (size_t)row * 512;
    const float* wh = Whh + (size_t)row * 512;
    const float* ir = is_[bb];
    const float* hr = hs[bb];
    float a0 = 0.f, a1 = 0.f, a2 = 0.f, a3 = 0.f;
    #pragma unroll 8
    for (int k = 0; k < 512; k += 4) {
        float4 wiv = *(const float4*)(wi + k);
        float4 iv = *(const float4*)(ir + k);
        float4 whv = *(const float4*)(wh + k);
        float4 hv = *(const float4*)(hr + k);
        a0 += wiv.x * iv.x + whv.x * hv.x;
        a1 += wiv.y * iv.y + whv.y * hv.y;
        a2 += wiv.z * iv.z + whv.z * hv.z;
        a3 += wiv.w * iv.w + whv.w * hv.w;
    }
    gacc[jj][bb][g] = bsum + (a0 + a1) + (a2 + a3);
    __syncthreads();
    if (tid < 64) {
        int ujj = tid >> 3, ubb = tid & 7;
        float2 hc = lstm_update(gacc[ujj][ubb][0], gacc[ujj][ubb][1],
                                gacc[ujj][ubb][2], gacc[ujj][ubb][3], creg);
        creg = hc.y;
        int ub = (bg << 3) + ubb, ujh = (jg << 3) + ujj;
        h_out[ub * 512 + ujh] = hc.x;
        if (seqout) seqout[(size_t)(ub * SDEC + t) * 512 + ujh] = hc.x;
    }
}

// ---------------------------------------------------------------------------
// Attention ('general') + combine for one batch element (device fn).
// ---------------------------------------------------------------------------
__device__ void attn_body(int b, int t,
                          const float* __restrict__ h2,
                          const float* __restrict__ enc_out,
                          const int* __restrict__ xs,
                          const int* __restrict__ ys,
                          const float* __restrict__ emb,
                          const float* __restrict__ attn_W,
                          const float* __restrict__ comb_W,
                          float* __restrict__ inp_out,
                          float* h2s, float* xc, float* hid,
                          float* pw, float* aw)
{
    int tid = threadIdx.x;
    int lane = tid & 63, wv = tid >> 6;
    int yt = ys[b * SDEC + t];

    for (int i = tid; i < 512; i += 256) {
        h2s[i] = h2[b * 512 + i];
        xc[i] = emb[(size_t)yt * EDIM + i];
    }
    __syncthreads();

    // hid = h2 @ attn_W^T   (wave-per-output, shuffle reduce)
    for (int e = wv; e < 512; e += 4) {
        const float* rowp = attn_W + (size_t)e * 512;
        float pp = 0.f;
        #pragma unroll
        for (int i = 0; i < 8; i++) pp += h2s[lane + 64 * i] * rowp[lane + 64 * i];
        pp = allreduce64(pp);
        if (lane == 0) hid[e] = pp;
    }
    __syncthreads();

    // pw[s] = hid . enc_out[b,s,:] - neg
    for (int s = wv; s < SENC; s += 4) {
        const float* rowp = enc_out + (size_t)(b * SENC + s) * 512;
        float pp = 0.f;
        #pragma unroll
        for (int i = 0; i < 8; i++) pp += hid[lane + 64 * i] * rowp[lane + 64 * i];
        pp = allreduce64(pp);
        if (lane == 0)
            pw[s] = pp - ((xs[b * SENC + s] > 0) ? 0.f : 1e20f);
    }
    __syncthreads();

    // softmax over 64 (single wave)
    if (tid < 64) {
        float v = pw[tid];
        float m = v;
        #pragma unroll
        for (int o = 1; o < 64; o <<= 1) m = fmaxf(m, __shfl_xor(m, o));
        float ex = expf(v - m);
        float sm = ex;
        #pragma unroll
        for (int o = 1; o < 64; o <<= 1) sm += __shfl_xor(sm, o);
        aw[tid] = ex / sm;
    }
    __syncthreads();

    // ctx[e] = sum_s aw[s] * enc_out[b,s,e]  (coalesced over e)
    for (int e = tid; e < 512; e += 256) {
        float s = 0.f;
        for (int ss = 0; ss < SENC; ss++)
            s += aw[ss] * enc_out[(size_t)(b * SENC + ss) * 512 + e];
        xc[512 + e] = s;
    }
    __syncthreads();

    // inp = tanh([xe,ctx] @ comb_W^T)
    for (int e = wv; e < 512; e += 4) {
        const float* rowp = comb_W + (size_t)e * 1024;
        float pp = 0.f;
        #pragma unroll
        for (int i = 0; i < 16; i++) pp += xc[lane + 64 * i] * rowp[lane + 64 * i];
        pp = allreduce64(pp);
        if (lane == 0) inp_out[b * 512 + e] = tanhf(pp);
    }
    // grid.sync() by caller publishes inp_out
}

// ---------------------------------------------------------------------------
// Persistent decoder: all 32 timesteps, 3 grid syncs per step:
//   A) attention (blocks 0..31, one per b) -> inpbuf
//   B) cell layer 0 (all 256 blocks)       -> dhb0[q]
//   C) cell layer 1 (all 256 blocks)       -> dhb1[q], h2seq
// c0/c1 held in registers; h parity-double-buffered in global.
// ---------------------------------------------------------------------------
__global__ __launch_bounds__(256) void decoder_persist(
    const int* __restrict__ xs, const int* __restrict__ ys,
    const float* __restrict__ emb, const float* __restrict__ enc_out,
    const float* __restrict__ attn_W, const float* __restrict__ comb_W,
    const float* __restrict__ Wih0, const float* __restrict__ Whh0,
    const float* __restrict__ bih0, const float* __restrict__ bhh0,
    const float* __restrict__ Wih1, const float* __restrict__ Whh1,
    const float* __restrict__ bih1, const float* __restrict__ bhh1,
    const float* __restrict__ hT0, const float* __restrict__ cT0,
    const float* __restrict__ hT1, const float* __restrict__ cT1,
    float* __restrict__ dhb0, float* __restrict__ dhb1,
    float* __restrict__ inpbuf, float* __restrict__ h2seq)
{
    __shared__ __align__(16) float hs[8][520];
    __shared__ __align__(16) float is_[8][520];
    __shared__ float gacc[8][8][4];
    __shared__ float h2s[512];
    __shared__ __align__(16) float xc[1024];
    __shared__ float hid[512];
    __shared__ float pw[64];
    __shared__ float aw[64];
    cg::grid_group grid = cg::this_grid();
    int blk = blockIdx.x;
    int jg = blk >> 2, bg = blk & 3;
    int tid = threadIdx.x;
    int r = tid >> 3;
    int g = r >> 3, jj = r & 7;
    int row = (g << 9) + (jg << 3) + jj;
    float bsum0 = bih0[row] + bhh0[row];
    float bsum1 = bih1[row] + bhh1[row];
    float c0 = 0.f, c1 = 0.f;
    if (tid < 64) {
        int ujj = tid >> 3, ubb = tid & 7;
        int ub = (bg << 3) + ubb, ujh = (jg << 3) + ujj;
        c0 = cT0[ub * 512 + ujh];
        c1 = cT1[ub * 512 + ujh];
    }
    int p = 0;
    for (int t = 0; t < SDEC; ++t) {
        int q = p ^ 1;
        // --- Phase A: attention ---
        if (blk < B) {
            attn_body(blk, t, (t == 0) ? hT1 : dhb1 + p * BH,
                      enc_out, xs, ys, emb, attn_W, comb_W, inpbuf,
                      h2s, xc, hid, pw, aw);
        }
        grid.sync();
        // --- Phase B: layer-0 cell ---
        cell_phase(Wih0, Whh0, bsum0, inpbuf,
                   (t == 0) ? hT0 : dhb0 + p * BH, dhb0 + q * BH,
                   (float*)nullptr, c0, t, jg, bg, row, hs, is_, gacc);
        grid.sync();
        // --- Phase C: layer-1 cell ---
        cell_phase(Wih1, Whh1, bsum1, dhb0 + q * BH,
                   (t == 0) ? hT1 : dhb1 + p * BH, dhb1 + q * BH,
                   h2seq, c1, t, jg, bg, row, hs, is_, gacc);
        grid.sync();
        p = q;
    }
}

// ---------------------------------------------------------------------------
// argmax over scores[m, 1:], lowest index on ties; preds[m] = index (float)
// ---------------------------------------------------------------------------
__global__ __launch_bounds__(256) void argmax_kernel(const float* __restrict__ scores,
                                                     float* __restrict__ preds)
{
    __shared__ float sv[256];
    __shared__ int si[256];
    int m = blockIdx.x;
    const float* row = scores + (size_t)m * VDIM;
    float best = -3.4e38f;
    int bi = 0x7fffffff;
    for (int v = 1 + (int)threadIdx.x; v < VDIM; v += 256) {
        float val = row[v];
        if (val > best) { best = val; bi = v; }   // ascending scan → lowest idx kept
    }
    sv[threadIdx.x] = best;
    si[threadIdx.x] = bi;
    __syncthreads();
    for (int s = 128; s > 0; s >>= 1) {
        if ((int)threadIdx.x < s) {
            float ov = sv[threadIdx.x + s];
            int oi = si[threadIdx.x + s];
            if (ov > sv[threadIdx.x] ||
                (ov == sv[threadIdx.x] && oi < si[threadIdx.x])) {
                sv[threadIdx.x] = ov;
                si[threadIdx.x] = oi;
            }
        }
        __syncthreads();
    }
    if (threadIdx.x == 0) preds[m] = (float)si[0];
}

// ---------------------------------------------------------------------------
extern "C" void kernel_launch(void* const* d_in, const int* in_sizes, int n_in,
                              void* d_out, int out_size, void* d_ws, size_t ws_size,
                              hipStream_t stream)
{
    const int* xs = (const int*)d_in[0];
    const int* ys = (const int*)d_in[1];
    const float* emb = (const float*)d_in[2];
    const float* W[16];
    for (int i = 0; i < 16; i++) W[i] = (const float*)d_in[3 + i];
    // enc layer l: W[l*4+{0:Wih,1:Whh,2:bih,3:bhh}] ; dec layer l: W[8+l*4+...]
    const float* attn_W = (const float*)d_in[19];
    const float* comb_W = (const float*)d_in[20];
    float* out = (float*)d_out;
    float* ws = (float*)d_ws;

    // workspace layout (floats)
    float* xemb  = ws;                   // 2048*512      = 1,048,576
    float* xg    = xemb + 1048576;       // 2048*2048     = 4,194,304
    float* l0out = xg + 4194304;         // 2048*512
    float* l1out = l0out + 1048576;      // 2048*512  (enc_out)
    float* ench  = l1out + 1048576;      // 2*BH   (encoder h parity buffer)
    float* hT    = ench + 2 * BH;        // 2*BH   (final h per layer)
    float* cT    = hT + 2 * BH;          // 2*BH   (final c per layer)
    // decoder buffers overlay xg (dead after encoder)
    float* h2seq  = xg;                  // 1024*512 = 524,288
    float* inpbuf = xg + 524288;         // BH
    float* dhb0   = inpbuf + BH;         // 2*BH parity
    float* dhb1   = dhb0 + 2 * BH;       // 2*BH parity

    // ---- Encoder ----
    embed_kernel<<<B * SENC, 128, 0, stream>>>(xs, emb, xemb);
    for (int l = 0; l < 2; l++) {
        gemm_nt<<<dim3(G4 / 64, (B * SENC) / 128), 256, 0, stream>>>(
            (l == 0) ? xemb : l0out, W[l * 4 + 0], xg,
            W[l * 4 + 2], W[l * 4 + 3], B * SENC, G4, 512);
        const float* xgp = xg;
        const float* whh = W[l * 4 + 1];
        float* seqo = (l == 0) ? l0out : l1out;
        float* hb = ench;
        float* hTl = hT + l * BH;
        float* cTl = cT + l * BH;
        void* eargs[] = {(void*)&xgp, (void*)&whh, (void*)&seqo,
                         (void*)&hb, (void*)&hTl, (void*)&cTl};
        hipLaunchCooperativeKernel((void*)enc_layer_persist, dim3(256), dim3(256),
                                   eargs, 0, stream);
    }

    // ---- Decoder (single persistent cooperative kernel) ----
    {
        const int* xs_ = xs;
        const int* ys_ = ys;
        const float* emb_ = emb;
        const float* enc_out_ = l1out;
        const float* attnW_ = attn_W;
        const float* combW_ = comb_W;
        const float* wih0 = W[8];
        const float* whh0 = W[9];
        const float* bih0 = W[10];
        const float* bhh0 = W[11];
        const float* wih1 = W[12];
        const float* whh1 = W[13];
        const float* bih1 = W[14];
        const float* bhh1 = W[15];
        const float* hT0_ = hT;
        const float* cT0_ = cT;
        const float* hT1_ = hT + BH;
        const float* cT1_ = cT + BH;
        float* dhb0_ = dhb0;
        float* dhb1_ = dhb1;
        float* inp_ = inpbuf;
        float* h2seq_ = h2seq;
        void* dargs[] = {(void*)&xs_, (void*)&ys_, (void*)&emb_, (void*)&enc_out_,
                         (void*)&attnW_, (void*)&combW_,
                         (void*)&wih0, (void*)&whh0, (void*)&bih0, (void*)&bhh0,
                         (void*)&wih1, (void*)&whh1, (void*)&bih1, (void*)&bhh1,
                         (void*)&hT0_, (void*)&cT0_, (void*)&hT1_, (void*)&cT1_,
                         (void*)&dhb0_, (void*)&dhb1_, (void*)&inp_, (void*)&h2seq_};
        hipLaunchCooperativeKernel((void*)decoder_persist, dim3(256), dim3(256),
                                   dargs, 0, stream);
    }

    // ---- Output projection + argmax ----
    gemm_nt<<<dim3(VDIM / 64, (B * SDEC) / 128), 256, 0, stream>>>(
        h2seq, emb, out + B * SDEC, nullptr, nullptr, B * SDEC, VDIM, 512);
    argmax_kernel<<<B * SDEC, 256, 0, stream>>>(out + B * SDEC, out);
}

// Round 2
// 10251.170 us; speedup vs baseline: 1.3859x; 1.3859x over previous
//
#include <hip/hip_runtime.h>
#include <math.h>

// Problem constants
#define B 32
#define SENC 64
#define SDEC 32
#define HDIM 512
#define EDIM 512
#define VDIM 32000
#define G4 2048              // 4*H
#define BH (B*HDIM)          // 16384
#define NBLK 256

// Agent-scope (cross-XCD coherent, L2-bypassing) accessors.
// These keep read-only weights L2-cached: no fences, no buffer_inv.
__device__ __forceinline__ float agent_ld(const float* p)
{
    return __hip_atomic_load((float*)p, __ATOMIC_RELAXED, __HIP_MEMORY_SCOPE_AGENT);
}
__device__ __forceinline__ void agent_st(float* p, float v)
{
    __hip_atomic_store(p, v, __ATOMIC_RELAXED, __HIP_MEMORY_SCOPE_AGENT);
}

// ---------------------------------------------------------------------------
// Lightweight grid barrier: monotonic agent-scope counter, relaxed spin.
// Prior agent-scope stores are write-through; vmcnt(0) drains them before
// arrival. No release/acquire fence -> L2 (weights) untouched.
// ---------------------------------------------------------------------------
__device__ __forceinline__ void grid_barrier(unsigned* cnt, unsigned target)
{
    asm volatile("s_waitcnt vmcnt(0) lgkmcnt(0)" ::: "memory");
    __syncthreads();
    if (threadIdx.x == 0) {
        __hip_atomic_fetch_add(cnt, 1u, __ATOMIC_RELAXED, __HIP_MEMORY_SCOPE_AGENT);
        while (__hip_atomic_load(cnt, __ATOMIC_RELAXED, __HIP_MEMORY_SCOPE_AGENT) < target)
            __builtin_amdgcn_s_sleep(2);
        asm volatile("" ::: "memory");
    }
    __syncthreads();
}

// ---------------------------------------------------------------------------
// embed: gather emb rows for a token sequence  (n_tok blocks x 128 threads)
// ---------------------------------------------------------------------------
__global__ __launch_bounds__(128) void embed_kernel(const int* __restrict__ toks,
                                                    const float* __restrict__ emb,
                                                    float* __restrict__ out)
{
    int t = blockIdx.x;
    int id = toks[t];
    const float4* src = (const float4*)(emb + (size_t)id * EDIM);
    float4* dst = (float4*)(out + (size_t)t * EDIM);
    dst[threadIdx.x] = src[threadIdx.x];   // 128 * float4 = 512 floats
}

// ---------------------------------------------------------------------------
// NT SGEMM: C[m,n] = sum_k A[m*K+k]*B[n*K+k] (+bias0[n]+bias1[n])
// block tile 128x128, 256 threads, 8x8 microtile. M%128==0, N%128==0, K%16==0.
// ---------------------------------------------------------------------------
__global__ __launch_bounds__(256) void gemm_nt128(const float* __restrict__ A,
                                                  const float* __restrict__ Bm,
                                                  float* __restrict__ C,
                                                  const float* __restrict__ bias0,
                                                  const float* __restrict__ bias1,
                                                  int M, int N, int K)
{
    __shared__ float As[16][128];
    __shared__ float Bs[16][128];
    int tid = threadIdx.x;
    int tx = tid & 15, ty = tid >> 4;            // 16 x 16 thread grid
    int m0 = blockIdx.y * 128, n0 = blockIdx.x * 128;

    float acc[8][8];
    #pragma unroll
    for (int i = 0; i < 8; i++)
        #pragma unroll
        for (int j = 0; j < 8; j++) acc[i][j] = 0.f;

    int lr = tid >> 1, lk = (tid & 1) * 8;       // row 0..127, k 0 or 8
    const float* Aptr = A + (size_t)(m0 + lr) * K + lk;
    const float* Bptr = Bm + (size_t)(n0 + lr) * K + lk;

    for (int k0 = 0; k0 < K; k0 += 16) {
        float4 a1 = *(const float4*)(Aptr + k0);
        float4 a2 = *(const float4*)(Aptr + k0 + 4);
        float4 b1 = *(const float4*)(Bptr + k0);
        float4 b2 = *(const float4*)(Bptr + k0 + 4);
        As[lk + 0][lr] = a1.x; As[lk + 1][lr] = a1.y;
        As[lk + 2][lr] = a1.z; As[lk + 3][lr] = a1.w;
        As[lk + 4][lr] = a2.x; As[lk + 5][lr] = a2.y;
        As[lk + 6][lr] = a2.z; As[lk + 7][lr] = a2.w;
        Bs[lk + 0][lr] = b1.x; Bs[lk + 1][lr] = b1.y;
        Bs[lk + 2][lr] = b1.z; Bs[lk + 3][lr] = b1.w;
        Bs[lk + 4][lr] = b2.x; Bs[lk + 5][lr] = b2.y;
        Bs[lk + 6][lr] = b2.z; Bs[lk + 7][lr] = b2.w;
        __syncthreads();
        #pragma unroll
        for (int kk = 0; kk < 16; kk++) {
            float4 av1 = *(const float4*)&As[kk][ty * 8];
            float4 av2 = *(const float4*)&As[kk][ty * 8 + 4];
            float4 bv1 = *(const float4*)&Bs[kk][tx * 8];
            float4 bv2 = *(const float4*)&Bs[kk][tx * 8 + 4];
            float am[8] = {av1.x, av1.y, av1.z, av1.w, av2.x, av2.y, av2.z, av2.w};
            float bn[8] = {bv1.x, bv1.y, bv1.z, bv1.w, bv2.x, bv2.y, bv2.z, bv2.w};
            #pragma unroll
            for (int i = 0; i < 8; i++)
                #pragma unroll
                for (int j = 0; j < 8; j++)
                    acc[i][j] += am[i] * bn[j];
        }
        __syncthreads();
    }

    int nc = n0 + tx * 8;
    float bb[8];
    #pragma unroll
    for (int j = 0; j < 8; j++) {
        bb[j] = 0.f;
        if (bias0) bb[j] += bias0[nc + j];
        if (bias1) bb[j] += bias1[nc + j];
    }
    #pragma unroll
    for (int i = 0; i < 8; i++) {
        int row = m0 + ty * 8 + i;
        float4 o1 = make_float4(acc[i][0] + bb[0], acc[i][1] + bb[1],
                                acc[i][2] + bb[2], acc[i][3] + bb[3]);
        float4 o2 = make_float4(acc[i][4] + bb[4], acc[i][5] + bb[5],
                                acc[i][6] + bb[6], acc[i][7] + bb[7]);
        *(float4*)(C + (size_t)row * N + nc) = o1;
        *(float4*)(C + (size_t)row * N + nc + 4) = o2;
    }
}

// ---------------------------------------------------------------------------
// helpers
// ---------------------------------------------------------------------------
__device__ __forceinline__ float allreduce64(float v)
{
    #pragma unroll
    for (int m = 1; m < 64; m <<= 1) v += __shfl_xor(v, m);
    return v;
}

__device__ __forceinline__ float2 lstm_update(float i_, float f_, float g_,
                                              float o_, float c)
{
    float ig = 1.f / (1.f + expf(-i_));
    float fg = 1.f / (1.f + expf(-f_));
    float gg = tanhf(g_);
    float og = 1.f / (1.f + expf(-o_));
    float cn = fg * c + ig * gg;
    float hn = og * tanhf(cn);
    return make_float2(hn, cn);
}

// ---------------------------------------------------------------------------
// Persistent encoder layer: all 64 timesteps in one cooperative-launched
// kernel, custom barrier. grid = 256 blocks = 64 jg x 4 bg, 256 threads.
// c state in registers of threads tid<64; h exchanged via agent-scope
// atomics in parity-double-buffered hbuf. Whh stays L2-cached (normal loads).
// ---------------------------------------------------------------------------
__global__ __launch_bounds__(256) void enc_layer_persist(
    const float* __restrict__ xg, const float* __restrict__ Whh,
    float* __restrict__ seq_out, float* __restrict__ hbuf,
    float* __restrict__ hT, float* __restrict__ cT,
    unsigned* __restrict__ cnt)
{
    __shared__ __align__(16) float hs[8][520];   // 520: rows offset 8 banks -> 2-way (free)
    __shared__ float gacc[8][8][4];              // [jj][bb][gate]
    int blk = blockIdx.x;
    int jg = blk >> 2, bg = blk & 3;
    int tid = threadIdx.x;
    int r = tid >> 3, bb = tid & 7;
    int g = r >> 3, jj = r & 7;
    int row = (g << 9) + (jg << 3) + jj;         // gate-row in [0,2048)
    int b = (bg << 3) + bb;
    const float* wrow = Whh + (size_t)row * 512;
    float creg = 0.f;
    unsigned ep = 0;
    int p = 0;
    for (int t = 0; t < SENC; ++t) {
        float accx = xg[(size_t)(b * SENC + t) * G4 + row];
        if (t == 0) {
            for (int i = tid; i < 8 * 512; i += 256) {
                int rb = i >> 9, kk = i & 511;
                hs[rb][kk] = 0.f;
            }
        } else {
            const float* src = hbuf + p * BH + ((bg << 3) << 9);
            for (int i = tid; i < 8 * 512; i += 256) {
                int rb = i >> 9, kk = i & 511;
                hs[rb][kk] = agent_ld(src + (rb << 9) + kk);
            }
        }
        __syncthreads();
        float a0 = 0.f, a1 = 0.f, a2 = 0.f, a3 = 0.f;
        const float* hr = hs[bb];
        #pragma unroll 8
        for (int k = 0; k < 512; k += 4) {
            float4 w = *(const float4*)(wrow + k);
            float4 h = *(const float4*)(hr + k);
            a0 += w.x * h.x; a1 += w.y * h.y;
            a2 += w.z * h.z; a3 += w.w * h.w;
        }
        gacc[jj][bb][g] = accx + (a0 + a1) + (a2 + a3);
        __syncthreads();
        if (tid < 64) {
            int ujj = tid >> 3, ubb = tid & 7;
            float2 hc = lstm_update(gacc[ujj][ubb][0], gacc[ujj][ubb][1],
                                    gacc[ujj][ubb][2], gacc[ujj][ubb][3], creg);
            creg = hc.y;
            int ub = (bg << 3) + ubb, ujh = (jg << 3) + ujj;
            agent_st(hbuf + (p ^ 1) * BH + ub * 512 + ujh, hc.x);
            seq_out[(size_t)(ub * SENC + t) * 512 + ujh] = hc.x;   // next-dispatch data
            if (t == SENC - 1) {
                hT[ub * 512 + ujh] = hc.x;
                cT[ub * 512 + ujh] = hc.y;
            }
        }
        ep++;
        grid_barrier(cnt, ep * NBLK);
        p ^= 1;
    }
}

// ---------------------------------------------------------------------------
// Decoder LSTM cell phase (device fn). Cross-block inputs via agent loads,
// outputs via agent stores; weights via normal (L2-cached) loads.
// ---------------------------------------------------------------------------
__device__ __forceinline__ void cell_phase(
    const float* __restrict__ Wih, const float* __restrict__ Whh,
    float bsum,
    const float* __restrict__ inp, const float* __restrict__ h_in,
    float* __restrict__ h_out, float* __restrict__ seqout,
    float& creg, int t, int jg, int bg, int row,
    float (*hs)[520], float (*is_)[520], float (*gacc)[8][4])
{
    int tid = threadIdx.x;
    {
        const float* hsrc = h_in + ((bg << 3) << 9);
        const float* isrc = inp + ((bg << 3) << 9);
        for (int i = tid; i < 8 * 512; i += 256) {
            int rb = i >> 9, kk = i & 511;
            hs[rb][kk] = agent_ld(hsrc + (rb << 9) + kk);
            is_[rb][kk] = agent_ld(isrc + (rb << 9) + kk);
        }
    }
    __syncthreads();
    int r = tid >> 3, bb = tid & 7;
    int g = r >> 3, jj = r & 7;
    const float* wi = Wih + (size_t)row * 512;
    const float* wh = Whh + (size_t)row * 512;
    const float* ir = is_[bb];
    const float* hr = hs[bb];
    float a0 = 0.f, a1 = 0.f, a2 = 0.f, a3 = 0.f;
    #pragma unroll 8
    for (int k = 0; k < 512; k += 4) {
        float4 wiv = *(const float4*)(wi + k);
        float4 iv = *(const float4*)(ir + k);
        float4 whv = *(const float4*)(wh + k);
        float4 hv = *(const float4*)(hr + k);
        a0 += wiv.x * iv.x + whv.x * hv.x;
        a1 += wiv.y * iv.y + whv.y * hv.y;
        a2 += wiv.z * iv.z + whv.z * hv.z;
        a3 += wiv.w * iv.w + whv.w * hv.w;
    }
    gacc[jj][bb][g] = bsum + (a0 + a1) + (a2 + a3);
    __syncthreads();
    if (tid < 64) {
        int ujj = tid >> 3, ubb = tid & 7;
        float2 hc = lstm_update(gacc[ujj][ubb][0], gacc[ujj][ubb][1],
                                gacc[ujj][ubb][2], gacc[ujj][ubb][3], creg);
        creg = hc.y;
        int ub = (bg << 3) + ubb, ujh = (jg << 3) + ujj;
        agent_st(h_out + ub * 512 + ujh, hc.x);
        if (seqout) seqout[(size_t)(ub * SDEC + t) * 512 + ujh] = hc.x;  // next dispatch
    }
}

// ---------------------------------------------------------------------------
// Attention ('general') + combine for one batch element (device fn).
// h2 (cross-block) via agent loads; enc_out/emb/weights normal cached loads.
// ---------------------------------------------------------------------------
__device__ void attn_body(int b, int t,
                          const float* __restrict__ h2,
                          const float* __restrict__ enc_out,
                          const int* __restrict__ xs,
                          const int* __restrict__ ys,
                          const float* __restrict__ emb,
                          const float* __restrict__ attn_W,
                          const float* __restrict__ comb_W,
                          float* __restrict__ inp_out,
                          float* h2s, float* xc, float* hid,
                          float* pw, float* aw)
{
    int tid = threadIdx.x;
    int lane = tid & 63, wv = tid >> 6;
    int yt = ys[b * SDEC + t];

    for (int i = tid; i < 512; i += 256) {
        h2s[i] = agent_ld(h2 + b * 512 + i);
        xc[i] = emb[(size_t)yt * EDIM + i];
    }
    __syncthreads();

    // hid = h2 @ attn_W^T   (wave-per-output, shuffle reduce)
    for (int e = wv; e < 512; e += 4) {
        const float* rowp = attn_W + (size_t)e * 512;
        float pp = 0.f;
        #pragma unroll
        for (int i = 0; i < 8; i++) pp += h2s[lane + 64 * i] * rowp[lane + 64 * i];
        pp = allreduce64(pp);
        if (lane == 0) hid[e] = pp;
    }
    __syncthreads();

    // pw[s] = hid . enc_out[b,s,:] - neg
    for (int s = wv; s < SENC; s += 4) {
        const float* rowp = enc_out + (size_t)(b * SENC + s) * 512;
        float pp = 0.f;
        #pragma unroll
        for (int i = 0; i < 8; i++) pp += hid[lane + 64 * i] * rowp[lane + 64 * i];
        pp = allreduce64(pp);
        if (lane == 0)
            pw[s] = pp - ((xs[b * SENC + s] > 0) ? 0.f : 1e20f);
    }
    __syncthreads();

    // softmax over 64 (single wave)
    if (tid < 64) {
        float v = pw[tid];
        float m = v;
        #pragma unroll
        for (int o = 1; o < 64; o <<= 1) m = fmaxf(m, __shfl_xor(m, o));
        float ex = expf(v - m);
        float sm = ex;
        #pragma unroll
        for (int o = 1; o < 64; o <<= 1) sm += __shfl_xor(sm, o);
        aw[tid] = ex / sm;
    }
    __syncthreads();

    // ctx[e] = sum_s aw[s] * enc_out[b,s,e]  (coalesced over e)
    for (int e = tid; e < 512; e += 256) {
        float s = 0.f;
        for (int ss = 0; ss < SENC; ss++)
            s += aw[ss] * enc_out[(size_t)(b * SENC + ss) * 512 + e];
        xc[512 + e] = s;
    }
    __syncthreads();

    // inp = tanh([xe,ctx] @ comb_W^T)
    for (int e = wv; e < 512; e += 4) {
        const float* rowp = comb_W + (size_t)e * 1024;
        float pp = 0.f;
        #pragma unroll
        for (int i = 0; i < 16; i++) pp += xc[lane + 64 * i] * rowp[lane + 64 * i];
        pp = allreduce64(pp);
        if (lane == 0) agent_st(inp_out + b * 512 + e, tanhf(pp));
    }
}

// ---------------------------------------------------------------------------
// Persistent decoder: all 32 timesteps, 3 custom barriers per step.
// ---------------------------------------------------------------------------
__global__ __launch_bounds__(256) void decoder_persist(
    const int* __restrict__ xs, const int* __restrict__ ys,
    const float* __restrict__ emb, const float* __restrict__ enc_out,
    const float* __restrict__ attn_W, const float* __restrict__ comb_W,
    const float* __restrict__ Wih0, const float* __restrict__ Whh0,
    const float* __restrict__ bih0, const float* __restrict__ bhh0,
    const float* __restrict__ Wih1, const float* __restrict__ Whh1,
    const float* __restrict__ bih1, const float* __restrict__ bhh1,
    const float* __restrict__ hT0, const float* __restrict__ cT0,
    const float* __restrict__ hT1, const float* __restrict__ cT1,
    float* __restrict__ dhb0, float* __restrict__ dhb1,
    float* __restrict__ inpbuf, float* __restrict__ h2seq,
    unsigned* __restrict__ cnt)
{
    __shared__ __align__(16) float hs[8][520];
    __shared__ __align__(16) float is_[8][520];
    __shared__ float gacc[8][8][4];
    __shared__ float h2s[512];
    __shared__ __align__(16) float xc[1024];
    __shared__ float hid[512];
    __shared__ float pw[64];
    __shared__ float aw[64];
    int blk = blockIdx.x;
    int jg = blk >> 2, bg = blk & 3;
    int tid = threadIdx.x;
    int r = tid >> 3;
    int g = r >> 3, jj = r & 7;
    int row = (g << 9) + (jg << 3) + jj;
    float bsum0 = bih0[row] + bhh0[row];
    float bsum1 = bih1[row] + bhh1[row];
    float c0 = 0.f, c1 = 0.f;
    if (tid < 64) {
        int ujj = tid >> 3, ubb = tid & 7;
        int ub = (bg << 3) + ubb, ujh = (jg << 3) + ujj;
        c0 = cT0[ub * 512 + ujh];
        c1 = cT1[ub * 512 + ujh];
    }
    unsigned ep = 0;
    int p = 0;
    for (int t = 0; t < SDEC; ++t) {
        int q = p ^ 1;
        // --- Phase A: attention (blocks 0..31) ---
        if (blk < B) {
            attn_body(blk, t, (t == 0) ? hT1 : dhb1 + p * BH,
                      enc_out, xs, ys, emb, attn_W, comb_W, inpbuf,
                      h2s, xc, hid, pw, aw);
        }
        ep++; grid_barrier(cnt, ep * NBLK);
        // --- Phase B: layer-0 cell ---
        cell_phase(Wih0, Whh0, bsum0, inpbuf,
                   (t == 0) ? hT0 : dhb0 + p * BH, dhb0 + q * BH,
                   (float*)nullptr, c0, t, jg, bg, row, hs, is_, gacc);
        ep++; grid_barrier(cnt, ep * NBLK);
        // --- Phase C: layer-1 cell ---
        cell_phase(Wih1, Whh1, bsum1, dhb0 + q * BH,
                   (t == 0) ? hT1 : dhb1 + p * BH, dhb1 + q * BH,
                   h2seq, c1, t, jg, bg, row, hs, is_, gacc);
        ep++; grid_barrier(cnt, ep * NBLK);
        p = q;
    }
}

// ---------------------------------------------------------------------------
// argmax over scores[m, 1:], lowest index on ties; preds[m] = index (float)
// ---------------------------------------------------------------------------
__global__ __launch_bounds__(256) void argmax_kernel(const float* __restrict__ scores,
                                                     float* __restrict__ preds)
{
    __shared__ float sv[256];
    __shared__ int si[256];
    int m = blockIdx.x;
    const float* row = scores + (size_t)m * VDIM;
    float best = -3.4e38f;
    int bi = 0x7fffffff;
    for (int v = 1 + (int)threadIdx.x; v < VDIM; v += 256) {
        float val = row[v];
        if (val > best) { best = val; bi = v; }   // ascending scan → lowest idx kept
    }
    sv[threadIdx.x] = best;
    si[threadIdx.x] = bi;
    __syncthreads();
    for (int s = 128; s > 0; s >>= 1) {
        if ((int)threadIdx.x < s) {
            float ov = sv[threadIdx.x + s];
            int oi = si[threadIdx.x + s];
            if (ov > sv[threadIdx.x] ||
                (ov == sv[threadIdx.x] && oi < si[threadIdx.x])) {
                sv[threadIdx.x] = ov;
                si[threadIdx.x] = oi;
            }
        }
        __syncthreads();
    }
    if (threadIdx.x == 0) preds[m] = (float)si[0];
}

// ---------------------------------------------------------------------------
extern "C" void kernel_launch(void* const* d_in, const int* in_sizes, int n_in,
                              void* d_out, int out_size, void* d_ws, size_t ws_size,
                              hipStream_t stream)
{
    const int* xs = (const int*)d_in[0];
    const int* ys = (const int*)d_in[1];
    const float* emb = (const float*)d_in[2];
    const float* W[16];
    for (int i = 0; i < 16; i++) W[i] = (const float*)d_in[3 + i];
    // enc layer l: W[l*4+{0:Wih,1:Whh,2:bih,3:bhh}] ; dec layer l: W[8+l*4+...]
    const float* attn_W = (const float*)d_in[19];
    const float* comb_W = (const float*)d_in[20];
    float* out = (float*)d_out;
    float* ws = (float*)d_ws;

    // workspace layout (floats)
    float* xemb  = ws;                   // 2048*512      = 1,048,576
    float* xg    = xemb + 1048576;       // 2048*2048     = 4,194,304
    float* l0out = xg + 4194304;         // 2048*512
    float* l1out = l0out + 1048576;      // 2048*512  (enc_out)
    float* ench  = l1out + 1048576;      // 2*BH   (encoder h parity buffer)
    float* hT    = ench + 2 * BH;        // 2*BH   (final h per layer)
    float* cT    = hT + 2 * BH;          // 2*BH   (final c per layer)
    unsigned* barcnt = (unsigned*)(cT + 2 * BH);   // 3 counters, 64B apart
    // decoder buffers overlay xg (dead after encoder)
    float* h2seq  = xg;                  // 1024*512 = 524,288
    float* inpbuf = xg + 524288;         // BH
    float* dhb0   = inpbuf + BH;         // 2*BH parity
    float* dhb1   = dhb0 + 2 * BH;       // 2*BH parity

    hipMemsetAsync(barcnt, 0, 192, stream);

    // ---- Encoder ----
    embed_kernel<<<B * SENC, 128, 0, stream>>>(xs, emb, xemb);
    for (int l = 0; l < 2; l++) {
        gemm_nt128<<<dim3(G4 / 128, (B * SENC) / 128), 256, 0, stream>>>(
            (l == 0) ? xemb : l0out, W[l * 4 + 0], xg,
            W[l * 4 + 2], W[l * 4 + 3], B * SENC, G4, 512);
        const float* xgp = xg;
        const float* whh = W[l * 4 + 1];
        float* seqo = (l == 0) ? l0out : l1out;
        float* hb = ench;
        float* hTl = hT + l * BH;
        float* cTl = cT + l * BH;
        unsigned* cnt = barcnt + l * 16;
        void* eargs[] = {(void*)&xgp, (void*)&whh, (void*)&seqo,
                         (void*)&hb, (void*)&hTl, (void*)&cTl, (void*)&cnt};
        hipLaunchCooperativeKernel((void*)enc_layer_persist, dim3(NBLK), dim3(256),
                                   eargs, 0, stream);
    }

    // ---- Decoder (single persistent kernel, custom barriers) ----
    {
        const int* xs_ = xs;
        const int* ys_ = ys;
        const float* emb_ = emb;
        const float* enc_out_ = l1out;
        const float* attnW_ = attn_W;
        const float* combW_ = comb_W;
        const float* wih0 = W[8];
        const float* whh0 = W[9];
        const float* bih0 = W[10];
        const float* bhh0 = W[11];
        const float* wih1 = W[12];
        const float* whh1 = W[13];
        const float* bih1 = W[14];
        const float* bhh1 = W[15];
        const float* hT0_ = hT;
        const float* cT0_ = cT;
        const float* hT1_ = hT + BH;
        const float* cT1_ = cT + BH;
        float* dhb0_ = dhb0;
        float* dhb1_ = dhb1;
        float* inp_ = inpbuf;
        float* h2seq_ = h2seq;
        unsigned* cnt = barcnt + 32;
        void* dargs[] = {(void*)&xs_, (void*)&ys_, (void*)&emb_, (void*)&enc_out_,
                         (void*)&attnW_, (void*)&combW_,
                         (void*)&wih0, (void*)&whh0, (void*)&bih0, (void*)&bhh0,
                         (void*)&wih1, (void*)&whh1, (void*)&bih1, (void*)&bhh1,
                         (void*)&hT0_, (void*)&cT0_, (void*)&hT1_, (void*)&cT1_,
                         (void*)&dhb0_, (void*)&dhb1_, (void*)&inp_, (void*)&h2seq_,
                         (void*)&cnt};
        hipLaunchCooperativeKernel((void*)decoder_persist, dim3(NBLK), dim3(256),
                                   dargs, 0, stream);
    }

    // ---- Output projection + argmax ----
    gemm_nt128<<<dim3(VDIM / 128, (B * SDEC) / 128), 256, 0, stream>>>(
        h2seq, emb, out + B * SDEC, nullptr, nullptr, B * SDEC, VDIM, 512);
    argmax_kernel<<<B * SDEC, 256, 0, stream>>>(out + B * SDEC, out);
}

// Round 3
// 6434.798 us; speedup vs baseline: 2.2079x; 1.5931x over previous
//
#include <hip/hip_runtime.h>
#include <math.h>

// Problem constants
#define B 32
#define SENC 64
#define SDEC 32
#define HDIM 512
#define EDIM 512
#define VDIM 32000
#define G4 2048              // 4*H
#define BH (B*HDIM)          // 16384
#define NBLK 256

// Agent-scope (cross-XCD coherent, L2-bypassing) accessors.
// Keep read-only weights on normal loads: they stay L2-cached.
__device__ __forceinline__ float agent_ld(const float* p)
{
    return __hip_atomic_load((float*)p, __ATOMIC_RELAXED, __HIP_MEMORY_SCOPE_AGENT);
}
__device__ __forceinline__ void agent_st(float* p, float v)
{
    __hip_atomic_store(p, v, __ATOMIC_RELAXED, __HIP_MEMORY_SCOPE_AGENT);
}

// ---------------------------------------------------------------------------
// Lightweight grid barrier: monotonic agent-scope counter, relaxed spin.
// vmcnt(0) drains prior (write-through) agent stores before arrival.
// No release/acquire fence -> L2-resident weights untouched.
// ---------------------------------------------------------------------------
__device__ __forceinline__ void grid_barrier(unsigned* cnt, unsigned target)
{
    asm volatile("s_waitcnt vmcnt(0) lgkmcnt(0)" ::: "memory");
    __syncthreads();
    if (threadIdx.x == 0) {
        __hip_atomic_fetch_add(cnt, 1u, __ATOMIC_RELAXED, __HIP_MEMORY_SCOPE_AGENT);
        while (__hip_atomic_load(cnt, __ATOMIC_RELAXED, __HIP_MEMORY_SCOPE_AGENT) < target)
            __builtin_amdgcn_s_sleep(2);
        asm volatile("" ::: "memory");
    }
    __syncthreads();
}

// ---------------------------------------------------------------------------
// embed: gather emb rows for a token sequence  (n_tok blocks x 128 threads)
// ---------------------------------------------------------------------------
__global__ __launch_bounds__(128) void embed_kernel(const int* __restrict__ toks,
                                                    const float* __restrict__ emb,
                                                    float* __restrict__ out)
{
    int t = blockIdx.x;
    int id = toks[t];
    const float4* src = (const float4*)(emb + (size_t)id * EDIM);
    float4* dst = (float4*)(out + (size_t)t * EDIM);
    dst[threadIdx.x] = src[threadIdx.x];   // 128 * float4 = 512 floats
}

// ---------------------------------------------------------------------------
// NT SGEMM: C[m,n] = sum_k A[m*K+k]*B[n*K+k] (+bias0[n]+bias1[n])
// block tile 128x128, 256 threads, 8x8 microtile. M%128==0, N%128==0, K%16==0.
// ---------------------------------------------------------------------------
__global__ __launch_bounds__(256) void gemm_nt128(const float* __restrict__ A,
                                                  const float* __restrict__ Bm,
                                                  float* __restrict__ C,
                                                  const float* __restrict__ bias0,
                                                  const float* __restrict__ bias1,
                                                  int M, int N, int K)
{
    __shared__ float As[16][128];
    __shared__ float Bs[16][128];
    int tid = threadIdx.x;
    int tx = tid & 15, ty = tid >> 4;            // 16 x 16 thread grid
    int m0 = blockIdx.y * 128, n0 = blockIdx.x * 128;

    float acc[8][8];
    #pragma unroll
    for (int i = 0; i < 8; i++)
        #pragma unroll
        for (int j = 0; j < 8; j++) acc[i][j] = 0.f;

    int lr = tid >> 1, lk = (tid & 1) * 8;       // row 0..127, k 0 or 8
    const float* Aptr = A + (size_t)(m0 + lr) * K + lk;
    const float* Bptr = Bm + (size_t)(n0 + lr) * K + lk;

    for (int k0 = 0; k0 < K; k0 += 16) {
        float4 a1 = *(const float4*)(Aptr + k0);
        float4 a2 = *(const float4*)(Aptr + k0 + 4);
        float4 b1 = *(const float4*)(Bptr + k0);
        float4 b2 = *(const float4*)(Bptr + k0 + 4);
        As[lk + 0][lr] = a1.x; As[lk + 1][lr] = a1.y;
        As[lk + 2][lr] = a1.z; As[lk + 3][lr] = a1.w;
        As[lk + 4][lr] = a2.x; As[lk + 5][lr] = a2.y;
        As[lk + 6][lr] = a2.z; As[lk + 7][lr] = a2.w;
        Bs[lk + 0][lr] = b1.x; Bs[lk + 1][lr] = b1.y;
        Bs[lk + 2][lr] = b1.z; Bs[lk + 3][lr] = b1.w;
        Bs[lk + 4][lr] = b2.x; Bs[lk + 5][lr] = b2.y;
        Bs[lk + 6][lr] = b2.z; Bs[lk + 7][lr] = b2.w;
        __syncthreads();
        #pragma unroll
        for (int kk = 0; kk < 16; kk++) {
            float4 av1 = *(const float4*)&As[kk][ty * 8];
            float4 av2 = *(const float4*)&As[kk][ty * 8 + 4];
            float4 bv1 = *(const float4*)&Bs[kk][tx * 8];
            float4 bv2 = *(const float4*)&Bs[kk][tx * 8 + 4];
            float am[8] = {av1.x, av1.y, av1.z, av1.w, av2.x, av2.y, av2.z, av2.w};
            float bn[8] = {bv1.x, bv1.y, bv1.z, bv1.w, bv2.x, bv2.y, bv2.z, bv2.w};
            #pragma unroll
            for (int i = 0; i < 8; i++)
                #pragma unroll
                for (int j = 0; j < 8; j++)
                    acc[i][j] += am[i] * bn[j];
        }
        __syncthreads();
    }

    int nc = n0 + tx * 8;
    float bb[8];
    #pragma unroll
    for (int j = 0; j < 8; j++) {
        bb[j] = 0.f;
        if (bias0) bb[j] += bias0[nc + j];
        if (bias1) bb[j] += bias1[nc + j];
    }
    #pragma unroll
    for (int i = 0; i < 8; i++) {
        int row = m0 + ty * 8 + i;
        float4 o1 = make_float4(acc[i][0] + bb[0], acc[i][1] + bb[1],
                                acc[i][2] + bb[2], acc[i][3] + bb[3]);
        float4 o2 = make_float4(acc[i][4] + bb[4], acc[i][5] + bb[5],
                                acc[i][6] + bb[6], acc[i][7] + bb[7]);
        *(float4*)(C + (size_t)row * N + nc) = o1;
        *(float4*)(C + (size_t)row * N + nc + 4) = o2;
    }
}

// ---------------------------------------------------------------------------
// helpers
// ---------------------------------------------------------------------------
__device__ __forceinline__ float allreduce64(float v)
{
    #pragma unroll
    for (int m = 1; m < 64; m <<= 1) v += __shfl_xor(v, m);
    return v;
}

__device__ __forceinline__ float2 lstm_update(float i_, float f_, float g_,
                                              float o_, float c)
{
    float ig = 1.f / (1.f + expf(-i_));
    float fg = 1.f / (1.f + expf(-f_));
    float gg = tanhf(g_);
    float og = 1.f / (1.f + expf(-o_));
    float cn = fg * c + ig * gg;
    float hn = og * tanhf(cn);
    return make_float2(hn, cn);
}

// ---------------------------------------------------------------------------
// Persistent encoder layer. grid = 256 blocks, 256 threads.
// XCD-aware roles (xcd = blk&7 round-robin): jg = xcd*8 + (slot>>2) so each
// XCD owns 8 contiguous jg groups -> 512 KB of Whh, L2-resident across steps.
// c state in registers of threads tid<64; h via agent-scope parity buffer.
// ---------------------------------------------------------------------------
__global__ __launch_bounds__(256) void enc_layer_persist(
    const float* __restrict__ xg, const float* __restrict__ Whh,
    float* __restrict__ seq_out, float* __restrict__ hbuf,
    float* __restrict__ hT, float* __restrict__ cT,
    unsigned* __restrict__ cnt)
{
    __shared__ __align__(16) float hs[8][520];   // 520: rows offset 8 banks -> 2-way (free)
    __shared__ float gacc[8][8][4];              // [jj][bb][gate]
    int blk = blockIdx.x;
    int xcd = blk & 7, slot = blk >> 3;
    int jg = xcd * 8 + (slot >> 2), bg = slot & 3;  // XCD-local weight rows
    int tid = threadIdx.x;
    int r = tid >> 3, bb = tid & 7;
    int g = r >> 3, jj = r & 7;
    int row = (g << 9) + (jg << 3) + jj;         // gate-row in [0,2048)
    int b = (bg << 3) + bb;
    const float* wrow = Whh + (size_t)row * 512;
    float creg = 0.f;
    unsigned ep = 0;
    int p = 0;
    for (int t = 0; t < SENC; ++t) {
        float accx = xg[(size_t)(b * SENC + t) * G4 + row];
        if (t == 0) {
            for (int i = tid; i < 8 * 512; i += 256) {
                int rb = i >> 9, kk = i & 511;
                hs[rb][kk] = 0.f;
            }
        } else {
            const float* src = hbuf + p * BH + ((bg << 3) << 9);
            for (int i = tid; i < 8 * 512; i += 256) {
                int rb = i >> 9, kk = i & 511;
                hs[rb][kk] = agent_ld(src + (rb << 9) + kk);
            }
        }
        __syncthreads();
        float a0 = 0.f, a1 = 0.f, a2 = 0.f, a3 = 0.f;
        const float* hr = hs[bb];
        #pragma unroll 8
        for (int k = 0; k < 512; k += 4) {
            float4 w = *(const float4*)(wrow + k);
            float4 h = *(const float4*)(hr + k);
            a0 += w.x * h.x; a1 += w.y * h.y;
            a2 += w.z * h.z; a3 += w.w * h.w;
        }
        gacc[jj][bb][g] = accx + (a0 + a1) + (a2 + a3);
        __syncthreads();
        if (tid < 64) {
            int ujj = tid >> 3, ubb = tid & 7;
            float2 hc = lstm_update(gacc[ujj][ubb][0], gacc[ujj][ubb][1],
                                    gacc[ujj][ubb][2], gacc[ujj][ubb][3], creg);
            creg = hc.y;
            int ub = (bg << 3) + ubb, ujh = (jg << 3) + ujj;
            agent_st(hbuf + (p ^ 1) * BH + ub * 512 + ujh, hc.x);
            seq_out[(size_t)(ub * SENC + t) * 512 + ujh] = hc.x;   // next-dispatch data
            if (t == SENC - 1) {
                hT[ub * 512 + ujh] = hc.x;
                cT[ub * 512 + ujh] = hc.y;
            }
        }
        ep++;
        grid_barrier(cnt, ep * NBLK);
        p ^= 1;
    }
}

// ---------------------------------------------------------------------------
// Decoder LSTM cell phase (device fn). Cross-block inputs via agent loads,
// outputs via agent stores; weights via normal (L2-resident) loads.
// ---------------------------------------------------------------------------
__device__ __forceinline__ void cell_phase(
    const float* __restrict__ Wih, const float* __restrict__ Whh,
    float bsum,
    const float* __restrict__ inp, const float* __restrict__ h_in,
    float* __restrict__ h_out, float* __restrict__ seqout,
    float& creg, int t, int jg, int bg, int row,
    float (*hs)[520], float (*is_)[520], float (*gacc)[8][4])
{
    int tid = threadIdx.x;
    {
        const float* hsrc = h_in + ((bg << 3) << 9);
        const float* isrc = inp + ((bg << 3) << 9);
        for (int i = tid; i < 8 * 512; i += 256) {
            int rb = i >> 9, kk = i & 511;
            hs[rb][kk] = agent_ld(hsrc + (rb << 9) + kk);
            is_[rb][kk] = agent_ld(isrc + (rb << 9) + kk);
        }
    }
    __syncthreads();
    int r = tid >> 3, bb = tid & 7;
    int g = r >> 3, jj = r & 7;
    const float* wi = Wih + (size_t)row * 512;
    const float* wh = Whh + (size_t)row * 512;
    const float* ir = is_[bb];
    const float* hr = hs[bb];
    float a0 = 0.f, a1 = 0.f, a2 = 0.f, a3 = 0.f;
    #pragma unroll 8
    for (int k = 0; k < 512; k += 4) {
        float4 wiv = *(const float4*)(wi + k);
        float4 iv = *(const float4*)(ir + k);
        float4 whv = *(const float4*)(wh + k);
        float4 hv = *(const float4*)(hr + k);
        a0 += wiv.x * iv.x + whv.x * hv.x;
        a1 += wiv.y * iv.y + whv.y * hv.y;
        a2 += wiv.z * iv.z + whv.z * hv.z;
        a3 += wiv.w * iv.w + whv.w * hv.w;
    }
    gacc[jj][bb][g] = bsum + (a0 + a1) + (a2 + a3);
    __syncthreads();
    if (tid < 64) {
        int ujj = tid >> 3, ubb = tid & 7;
        float2 hc = lstm_update(gacc[ujj][ubb][0], gacc[ujj][ubb][1],
                                gacc[ujj][ubb][2], gacc[ujj][ubb][3], creg);
        creg = hc.y;
        int ub = (bg << 3) + ubb, ujh = (jg << 3) + ujj;
        agent_st(h_out + ub * 512 + ujh, hc.x);
        if (seqout) seqout[(size_t)(ub * SDEC + t) * 512 + ujh] = hc.x;  // next dispatch
    }
    __syncthreads();
}

// ---------------------------------------------------------------------------
// Persistent decoder: all 32 timesteps, 5 barriers per step.
// Attention distributed across all 256 blocks, e-sliced by XCD so attn_W /
// comb_W slices (128 KB / 256 KB per XCD) stay L2-resident:
//   A1 (256 blk): hid[b, e-slice] = h2[b] @ attn_W[e-slice]^T
//   A2 (32 blk):  pw -> softmax -> ctx[b] (enc_out b-slices pinned per XCD)
//   A3 (256 blk): inp[b, e-slice] = tanh([xe|ctx] @ comb_W[e-slice]^T)
//   B, C: LSTM cells, jg row-groups pinned per XCD (2 MB weights/XCD).
// ---------------------------------------------------------------------------
__global__ __launch_bounds__(256) void decoder_persist(
    const int* __restrict__ xs, const float* __restrict__ yemb,
    const float* __restrict__ enc_out,
    const float* __restrict__ attn_W, const float* __restrict__ comb_W,
    const float* __restrict__ Wih0, const float* __restrict__ Whh0,
    const float* __restrict__ bih0, const float* __restrict__ bhh0,
    const float* __restrict__ Wih1, const float* __restrict__ Whh1,
    const float* __restrict__ bih1, const float* __restrict__ bhh1,
    const float* __restrict__ hT0, const float* __restrict__ cT0,
    const float* __restrict__ hT1, const float* __restrict__ cT1,
    float* __restrict__ dhb0, float* __restrict__ dhb1,
    float* __restrict__ inpbuf, float* __restrict__ h2seq,
    float* __restrict__ hidb, float* __restrict__ xcb,
    unsigned* __restrict__ cnt)
{
    __shared__ __align__(16) float hs[8][520];
    __shared__ __align__(16) float is_[8][520];
    __shared__ float gacc[8][8][4];
    __shared__ float h2s[512];
    __shared__ __align__(16) float xcs[1024];
    __shared__ float pw[64];
    __shared__ float aw[64];
    int blk = blockIdx.x;
    int xcd = blk & 7, slot = blk >> 3;
    // cell role: XCD owns jg in [xcd*8, xcd*8+8)
    int jg = xcd * 8 + (slot >> 2), bg = slot & 3;
    // attention role: XCD owns e-slice [xcd*64, xcd*64+64); block handles b=slot
    int ab = slot;
    int e0 = xcd << 6;
    int tid = threadIdx.x;
    int lane = tid & 63, wv = tid >> 6;
    int r = tid >> 3;
    int g = r >> 3, jj = r & 7;
    int row = (g << 9) + (jg << 3) + jj;
    float bsum0 = bih0[row] + bhh0[row];
    float bsum1 = bih1[row] + bhh1[row];
    float c0 = 0.f, c1 = 0.f;
    if (tid < 64) {
        int ujj = tid >> 3, ubb = tid & 7;
        int ub = (bg << 3) + ubb, ujh = (jg << 3) + ujj;
        c0 = cT0[ub * 512 + ujh];
        c1 = cT1[ub * 512 + ujh];
    }
    unsigned ep = 0;
    int p = 0;
    for (int t = 0; t < SDEC; ++t) {
        int q = p ^ 1;
        // ---- A1: hid[ab, e0:e0+64) ----
        {
            const float* h2p = ((t == 0) ? hT1 : dhb1 + p * BH) + ab * 512;
            for (int i = tid; i < 512; i += 256) h2s[i] = agent_ld(h2p + i);
            __syncthreads();
            for (int e = wv; e < 64; e += 4) {
                const float* rowp = attn_W + (size_t)(e0 + e) * 512;
                float pp = 0.f;
                #pragma unroll
                for (int i = 0; i < 8; i++)
                    pp += h2s[lane + 64 * i] * rowp[lane + 64 * i];
                pp = allreduce64(pp);
                if (lane == 0) agent_st(hidb + ab * 512 + e0 + e, pp);
            }
        }
        ep++; grid_barrier(cnt, ep * NBLK);
        // ---- A2: pw/softmax/ctx for b = xcd*4 + slot (blocks 0..31) ----
        if (blk < 32) {
            int b = xcd * 4 + slot;    // 4 b per XCD -> enc_out slices resident
            for (int i = tid; i < 512; i += 256) h2s[i] = agent_ld(hidb + b * 512 + i);
            __syncthreads();
            for (int s = wv; s < SENC; s += 4) {
                const float* rowp = enc_out + (size_t)(b * SENC + s) * 512;
                float pp = 0.f;
                #pragma unroll
                for (int i = 0; i < 8; i++)
                    pp += h2s[lane + 64 * i] * rowp[lane + 64 * i];
                pp = allreduce64(pp);
                if (lane == 0)
                    pw[s] = pp - ((xs[b * SENC + s] > 0) ? 0.f : 1e20f);
            }
            __syncthreads();
            if (tid < 64) {
                float v = pw[tid];
                float m = v;
                #pragma unroll
                for (int o = 1; o < 64; o <<= 1) m = fmaxf(m, __shfl_xor(m, o));
                float ex = expf(v - m);
                float sm = ex;
                #pragma unroll
                for (int o = 1; o < 64; o <<= 1) sm += __shfl_xor(sm, o);
                aw[tid] = ex / sm;
            }
            __syncthreads();
            for (int e = tid; e < 512; e += 256) {
                float s = 0.f;
                for (int ss = 0; ss < SENC; ss++)
                    s += aw[ss] * enc_out[(size_t)(b * SENC + ss) * 512 + e];
                agent_st(xcb + b * 512 + e, s);
            }
        }
        ep++; grid_barrier(cnt, ep * NBLK);
        // ---- A3: inp[ab, e0:e0+64) = tanh([xe|ctx] @ comb_W^T) ----
        {
            const float* yrow = yemb + (size_t)(ab * SDEC + t) * 512;  // read-only, cached
            for (int i = tid; i < 512; i += 256) {
                xcs[i] = yrow[i];
                xcs[512 + i] = agent_ld(xcb + ab * 512 + i);
            }
            __syncthreads();
            for (int e = wv; e < 64; e += 4) {
                const float* rowp = comb_W + (size_t)(e0 + e) * 1024;
                float pp = 0.f;
                #pragma unroll
                for (int i = 0; i < 16; i++)
                    pp += xcs[lane + 64 * i] * rowp[lane + 64 * i];
                pp = allreduce64(pp);
                if (lane == 0) agent_st(inpbuf + ab * 512 + e0 + e, tanhf(pp));
            }
        }
        ep++; grid_barrier(cnt, ep * NBLK);
        // ---- B: layer-0 cell ----
        cell_phase(Wih0, Whh0, bsum0, inpbuf,
                   (t == 0) ? hT0 : dhb0 + p * BH, dhb0 + q * BH,
                   (float*)nullptr, c0, t, jg, bg, row, hs, is_, gacc);
        ep++; grid_barrier(cnt, ep * NBLK);
        // ---- C: layer-1 cell ----
        cell_phase(Wih1, Whh1, bsum1, dhb0 + q * BH,
                   (t == 0) ? hT1 : dhb1 + p * BH, dhb1 + q * BH,
                   h2seq, c1, t, jg, bg, row, hs, is_, gacc);
        ep++; grid_barrier(cnt, ep * NBLK);
        p = q;
    }
}

// ---------------------------------------------------------------------------
// argmax over scores[m, 1:], lowest index on ties; preds[m] = index (float)
// ---------------------------------------------------------------------------
__global__ __launch_bounds__(256) void argmax_kernel(const float* __restrict__ scores,
                                                     float* __restrict__ preds)
{
    __shared__ float sv[256];
    __shared__ int si[256];
    int m = blockIdx.x;
    const float* row = scores + (size_t)m * VDIM;
    float best = -3.4e38f;
    int bi = 0x7fffffff;
    for (int v = 1 + (int)threadIdx.x; v < VDIM; v += 256) {
        float val = row[v];
        if (val > best) { best = val; bi = v; }   // ascending scan → lowest idx kept
    }
    sv[threadIdx.x] = best;
    si[threadIdx.x] = bi;
    __syncthreads();
    for (int s = 128; s > 0; s >>= 1) {
        if ((int)threadIdx.x < s) {
            float ov = sv[threadIdx.x + s];
            int oi = si[threadIdx.x + s];
            if (ov > sv[threadIdx.x] ||
                (ov == sv[threadIdx.x] && oi < si[threadIdx.x])) {
                sv[threadIdx.x] = ov;
                si[threadIdx.x] = oi;
            }
        }
        __syncthreads();
    }
    if (threadIdx.x == 0) preds[m] = (float)si[0];
}

// ---------------------------------------------------------------------------
extern "C" void kernel_launch(void* const* d_in, const int* in_sizes, int n_in,
                              void* d_out, int out_size, void* d_ws, size_t ws_size,
                              hipStream_t stream)
{
    const int* xs = (const int*)d_in[0];
    const int* ys = (const int*)d_in[1];
    const float* emb = (const float*)d_in[2];
    const float* W[16];
    for (int i = 0; i < 16; i++) W[i] = (const float*)d_in[3 + i];
    // enc layer l: W[l*4+{0:Wih,1:Whh,2:bih,3:bhh}] ; dec layer l: W[8+l*4+...]
    const float* attn_W = (const float*)d_in[19];
    const float* comb_W = (const float*)d_in[20];
    float* out = (float*)d_out;
    float* ws = (float*)d_ws;

    // workspace layout (floats)
    float* xemb  = ws;                   // 2048*512      = 1,048,576
    float* xg    = xemb + 1048576;       // 2048*2048     = 4,194,304
    float* l0out = xg + 4194304;         // 2048*512
    float* l1out = l0out + 1048576;      // 2048*512  (enc_out)
    float* ench  = l1out + 1048576;      // 2*BH   (encoder h parity buffer)
    float* hT    = ench + 2 * BH;        // 2*BH   (final h per layer)
    float* cT    = hT + 2 * BH;          // 2*BH   (final c per layer)
    unsigned* barcnt = (unsigned*)(cT + 2 * BH);   // 3 counters, 64B apart
    // ys embeddings overlay xemb (dead after layer-0 pre-gate GEMM)
    float* yemb   = xemb;                // 1024*512 = 524,288
    // decoder buffers overlay xg (dead after encoder)
    float* h2seq  = xg;                  // 1024*512 = 524,288
    float* inpbuf = xg + 524288;         // BH
    float* dhb0   = inpbuf + BH;         // 2*BH parity
    float* dhb1   = dhb0 + 2 * BH;       // 2*BH parity
    float* hidb   = dhb1 + 2 * BH;       // BH
    float* xcb    = hidb + BH;           // BH (ctx only; xe read from yemb)

    hipMemsetAsync(barcnt, 0, 192, stream);

    // ---- Encoder ----
    embed_kernel<<<B * SENC, 128, 0, stream>>>(xs, emb, xemb);
    for (int l = 0; l < 2; l++) {
        gemm_nt128<<<dim3(G4 / 128, (B * SENC) / 128), 256, 0, stream>>>(
            (l == 0) ? xemb : l0out, W[l * 4 + 0], xg,
            W[l * 4 + 2], W[l * 4 + 3], B * SENC, G4, 512);
        if (l == 0) {
            // xemb is dead now; fill ys embeddings into the same region
            embed_kernel<<<B * SDEC, 128, 0, stream>>>(ys, emb, yemb);
        }
        const float* xgp = xg;
        const float* whh = W[l * 4 + 1];
        float* seqo = (l == 0) ? l0out : l1out;
        float* hb = ench;
        float* hTl = hT + l * BH;
        float* cTl = cT + l * BH;
        unsigned* cnt = barcnt + l * 16;
        void* eargs[] = {(void*)&xgp, (void*)&whh, (void*)&seqo,
                         (void*)&hb, (void*)&hTl, (void*)&cTl, (void*)&cnt};
        hipLaunchCooperativeKernel((void*)enc_layer_persist, dim3(NBLK), dim3(256),
                                   eargs, 0, stream);
    }

    // ---- Decoder (single persistent kernel, custom barriers) ----
    {
        const int* xs_ = xs;
        const float* yemb_ = yemb;
        const float* enc_out_ = l1out;
        const float* attnW_ = attn_W;
        const float* combW_ = comb_W;
        const float* wih0 = W[8];
        const float* whh0 = W[9];
        const float* bih0 = W[10];
        const float* bhh0 = W[11];
        const float* wih1 = W[12];
        const float* whh1 = W[13];
        const float* bih1 = W[14];
        const float* bhh1 = W[15];
        const float* hT0_ = hT;
        const float* cT0_ = cT;
        const float* hT1_ = hT + BH;
        const float* cT1_ = cT + BH;
        float* dhb0_ = dhb0;
        float* dhb1_ = dhb1;
        float* inp_ = inpbuf;
        float* h2seq_ = h2seq;
        float* hidb_ = hidb;
        float* xcb_ = xcb;
        unsigned* cnt = barcnt + 32;
        void* dargs[] = {(void*)&xs_, (void*)&yemb_, (void*)&enc_out_,
                         (void*)&attnW_, (void*)&combW_,
                         (void*)&wih0, (void*)&whh0, (void*)&bih0, (void*)&bhh0,
                         (void*)&wih1, (void*)&whh1, (void*)&bih1, (void*)&bhh1,
                         (void*)&hT0_, (void*)&cT0_, (void*)&hT1_, (void*)&cT1_,
                         (void*)&dhb0_, (void*)&dhb1_, (void*)&inp_, (void*)&h2seq_,
                         (void*)&hidb_, (void*)&xcb_, (void*)&cnt};
        hipLaunchCooperativeKernel((void*)decoder_persist, dim3(NBLK), dim3(256),
                                   dargs, 0, stream);
    }

    // ---- Output projection + argmax ----
    gemm_nt128<<<dim3(VDIM / 128, (B * SDEC) / 128), 256, 0, stream>>>(
        h2seq, emb, out + B * SDEC, nullptr, nullptr, B * SDEC, VDIM, 512);
    argmax_kernel<<<B * SDEC, 256, 0, stream>>>(out + B * SDEC, out);
}

// Round 4
// 4452.630 us; speedup vs baseline: 3.1907x; 1.4452x over previous
//
#include <hip/hip_runtime.h>
#include <math.h>

// Problem constants
#define B 32
#define SENC 64
#define SDEC 32
#define HDIM 512
#define EDIM 512
#define VDIM 32000
#define G4 2048              // 4*H
#define BH (B*HDIM)          // 16384
#define NBLK 256

// ---------------------------------------------------------------------------
// Coherent (cross-XCD) accessors. Scalar via compiler atomics; vector via
// inline asm with sc0 sc1 (system scope: bypasses L1+L2, reads/writes the
// coherence point). Read-only weights use normal loads -> stay L2-cached.
// ---------------------------------------------------------------------------
__device__ __forceinline__ float agent_ld(const float* p)
{
    return __hip_atomic_load((float*)p, __ATOMIC_RELAXED, __HIP_MEMORY_SCOPE_AGENT);
}
__device__ __forceinline__ void agent_st(float* p, float v)
{
    __hip_atomic_store(p, v, __ATOMIC_RELAXED, __HIP_MEMORY_SCOPE_AGENT);
}
// Issue-only vector coherent load: caller MUST execute
// asm volatile("s_waitcnt vmcnt(0)" ::: "memory") before using the result.
__device__ __forceinline__ float4 agent_ld4(const float* p)
{
    float4 v;
    asm volatile("global_load_dwordx4 %0, %1, off sc0 sc1"
                 : "=v"(v) : "v"(p) : "memory");
    return v;
}

// ---------------------------------------------------------------------------
// Hierarchical grid barrier (256 blocks = 8 XCD-groups x 32).
//  1) arrive: atomic add on per-XCD counter (8 parallel lines)
//  2) last arriver of each XCD adds to global counter, spins till 8 arrived
//  3) each XCD master sets its XCD release flag (epoch value)
//  4) others spin read-only on their XCD's flag
// Monotonic epochs -> no resets. vmcnt(0) drains coherent stores first.
// Layout (dwords): xcnt at xcd*16, gcnt at 256, rflag at 512+xcd*16.
// ---------------------------------------------------------------------------
__device__ __forceinline__ void grid_barrier_h(unsigned* bar, int xcd, unsigned ep)
{
    asm volatile("s_waitcnt vmcnt(0) lgkmcnt(0)" ::: "memory");
    __syncthreads();
    if (threadIdx.x == 0) {
        unsigned* xcnt = bar + xcd * 16;
        unsigned* gcnt = bar + 256;
        unsigned* rfl  = bar + 512 + xcd * 16;
        unsigned prev = __hip_atomic_fetch_add(xcnt, 1u, __ATOMIC_RELAXED,
                                               __HIP_MEMORY_SCOPE_AGENT);
        if (prev == ep * 32u - 1u) {
            __hip_atomic_fetch_add(gcnt, 1u, __ATOMIC_RELAXED,
                                   __HIP_MEMORY_SCOPE_AGENT);
            while (__hip_atomic_load(gcnt, __ATOMIC_RELAXED,
                                     __HIP_MEMORY_SCOPE_AGENT) < ep * 8u)
                __builtin_amdgcn_s_sleep(1);
            __hip_atomic_store(rfl, ep, __ATOMIC_RELAXED,
                               __HIP_MEMORY_SCOPE_AGENT);
        } else {
            while (__hip_atomic_load(rfl, __ATOMIC_RELAXED,
                                     __HIP_MEMORY_SCOPE_AGENT) < ep)
                __builtin_amdgcn_s_sleep(2);
        }
        asm volatile("" ::: "memory");
    }
    __syncthreads();
}

// ---------------------------------------------------------------------------
// embed: gather emb rows for a token sequence  (n_tok blocks x 128 threads)
// ---------------------------------------------------------------------------
__global__ __launch_bounds__(128) void embed_kernel(const int* __restrict__ toks,
                                                    const float* __restrict__ emb,
                                                    float* __restrict__ out)
{
    int t = blockIdx.x;
    int id = toks[t];
    const float4* src = (const float4*)(emb + (size_t)id * EDIM);
    float4* dst = (float4*)(out + (size_t)t * EDIM);
    dst[threadIdx.x] = src[threadIdx.x];   // 128 * float4 = 512 floats
}

// ---------------------------------------------------------------------------
// NT SGEMM: C[m,n] = sum_k A[m*K+k]*B[n*K+k] (+bias0[n]+bias1[n])
// block tile 128x128, 256 threads, 8x8 microtile. M%128==0, N%128==0, K%16==0.
// ---------------------------------------------------------------------------
__global__ __launch_bounds__(256) void gemm_nt128(const float* __restrict__ A,
                                                  const float* __restrict__ Bm,
                                                  float* __restrict__ C,
                                                  const float* __restrict__ bias0,
                                                  const float* __restrict__ bias1,
                                                  int M, int N, int K)
{
    __shared__ float As[16][128];
    __shared__ float Bs[16][128];
    int tid = threadIdx.x;
    int tx = tid & 15, ty = tid >> 4;            // 16 x 16 thread grid
    int m0 = blockIdx.y * 128, n0 = blockIdx.x * 128;

    float acc[8][8];
    #pragma unroll
    for (int i = 0; i < 8; i++)
        #pragma unroll
        for (int j = 0; j < 8; j++) acc[i][j] = 0.f;

    int lr = tid >> 1, lk = (tid & 1) * 8;       // row 0..127, k 0 or 8
    const float* Aptr = A + (size_t)(m0 + lr) * K + lk;
    const float* Bptr = Bm + (size_t)(n0 + lr) * K + lk;

    for (int k0 = 0; k0 < K; k0 += 16) {
        float4 a1 = *(const float4*)(Aptr + k0);
        float4 a2 = *(const float4*)(Aptr + k0 + 4);
        float4 b1 = *(const float4*)(Bptr + k0);
        float4 b2 = *(const float4*)(Bptr + k0 + 4);
        As[lk + 0][lr] = a1.x; As[lk + 1][lr] = a1.y;
        As[lk + 2][lr] = a1.z; As[lk + 3][lr] = a1.w;
        As[lk + 4][lr] = a2.x; As[lk + 5][lr] = a2.y;
        As[lk + 6][lr] = a2.z; As[lk + 7][lr] = a2.w;
        Bs[lk + 0][lr] = b1.x; Bs[lk + 1][lr] = b1.y;
        Bs[lk + 2][lr] = b1.z; Bs[lk + 3][lr] = b1.w;
        Bs[lk + 4][lr] = b2.x; Bs[lk + 5][lr] = b2.y;
        Bs[lk + 6][lr] = b2.z; Bs[lk + 7][lr] = b2.w;
        __syncthreads();
        #pragma unroll
        for (int kk = 0; kk < 16; kk++) {
            float4 av1 = *(const float4*)&As[kk][ty * 8];
            float4 av2 = *(const float4*)&As[kk][ty * 8 + 4];
            float4 bv1 = *(const float4*)&Bs[kk][tx * 8];
            float4 bv2 = *(const float4*)&Bs[kk][tx * 8 + 4];
            float am[8] = {av1.x, av1.y, av1.z, av1.w, av2.x, av2.y, av2.z, av2.w};
            float bn[8] = {bv1.x, bv1.y, bv1.z, bv1.w, bv2.x, bv2.y, bv2.z, bv2.w};
            #pragma unroll
            for (int i = 0; i < 8; i++)
                #pragma unroll
                for (int j = 0; j < 8; j++)
                    acc[i][j] += am[i] * bn[j];
        }
        __syncthreads();
    }

    int nc = n0 + tx * 8;
    float bb[8];
    #pragma unroll
    for (int j = 0; j < 8; j++) {
        bb[j] = 0.f;
        if (bias0) bb[j] += bias0[nc + j];
        if (bias1) bb[j] += bias1[nc + j];
    }
    #pragma unroll
    for (int i = 0; i < 8; i++) {
        int row = m0 + ty * 8 + i;
        float4 o1 = make_float4(acc[i][0] + bb[0], acc[i][1] + bb[1],
                                acc[i][2] + bb[2], acc[i][3] + bb[3]);
        float4 o2 = make_float4(acc[i][4] + bb[4], acc[i][5] + bb[5],
                                acc[i][6] + bb[6], acc[i][7] + bb[7]);
        *(float4*)(C + (size_t)row * N + nc) = o1;
        *(float4*)(C + (size_t)row * N + nc + 4) = o2;
    }
}

// ---------------------------------------------------------------------------
// helpers
// ---------------------------------------------------------------------------
__device__ __forceinline__ float allreduce64(float v)
{
    #pragma unroll
    for (int m = 1; m < 64; m <<= 1) v += __shfl_xor(v, m);
    return v;
}

__device__ __forceinline__ float2 lstm_update(float i_, float f_, float g_,
                                              float o_, float c)
{
    float ig = 1.f / (1.f + expf(-i_));
    float fg = 1.f / (1.f + expf(-f_));
    float gg = tanhf(g_);
    float og = 1.f / (1.f + expf(-o_));
    float cn = fg * c + ig * gg;
    float hn = og * tanhf(cn);
    return make_float2(hn, cn);
}

// ---------------------------------------------------------------------------
// Persistent encoder layer. grid = 256 blocks (8 XCD x 32), 256 threads.
// XCD owns 8 contiguous jg groups -> Whh slice L2-resident across steps.
// c state in registers of threads tid<64; h via coherent parity buffer.
// ---------------------------------------------------------------------------
__global__ __launch_bounds__(256) void enc_layer_persist(
    const float* __restrict__ xg, const float* __restrict__ Whh,
    float* __restrict__ seq_out, float* __restrict__ hbuf,
    float* __restrict__ hT, float* __restrict__ cT,
    unsigned* __restrict__ bar)
{
    __shared__ __align__(16) float hs[8][520];   // 520: 2-way bank alias (free)
    __shared__ float gacc[8][8][5];              // [jj][bb][gate], padded
    int blk = blockIdx.x;
    int xcd = blk & 7, slot = blk >> 3;
    int jg = xcd * 8 + (slot >> 2), bg = slot & 3;  // XCD-local weight rows
    int tid = threadIdx.x;
    int r = tid >> 3, bb = tid & 7;
    int g = r >> 3, jj = r & 7;
    int row = (g << 9) + (jg << 3) + jj;         // gate-row in [0,2048)
    int b = (bg << 3) + bb;
    const float* wrow = Whh + (size_t)row * 512;
    float creg = 0.f;
    unsigned ep = 0;
    int p = 0;
    for (int t = 0; t < SENC; ++t) {
        float accx = xg[(size_t)(b * SENC + t) * G4 + row];
        if (t == 0) {
            float4 z = make_float4(0.f, 0.f, 0.f, 0.f);
            #pragma unroll
            for (int u = 0; u < 4; u++) {
                int d = (tid + (u << 8)) << 2;
                *(float4*)&hs[d >> 9][d & 511] = z;
            }
        } else {
            const float4* src4 = (const float4*)(hbuf + p * BH + ((bg << 3) << 9));
            float4 hv4[4];
            #pragma unroll
            for (int u = 0; u < 4; u++)
                hv4[u] = agent_ld4((const float*)(src4 + tid + (u << 8)));
            asm volatile("s_waitcnt vmcnt(0)" ::: "memory");
            #pragma unroll
            for (int u = 0; u < 4; u++) {
                int d = (tid + (u << 8)) << 2;
                *(float4*)&hs[d >> 9][d & 511] = hv4[u];
            }
        }
        __syncthreads();
        float a0 = 0.f, a1 = 0.f, a2 = 0.f, a3 = 0.f;
        const float* hr = hs[bb];
        #pragma unroll 8
        for (int k = 0; k < 512; k += 4) {
            float4 w = *(const float4*)(wrow + k);
            float4 h = *(const float4*)(hr + k);
            a0 += w.x * h.x; a1 += w.y * h.y;
            a2 += w.z * h.z; a3 += w.w * h.w;
        }
        gacc[jj][bb][g] = accx + (a0 + a1) + (a2 + a3);
        __syncthreads();
        if (tid < 64) {
            // ujj = tid&7 -> consecutive lanes write consecutive ujh: 32B bursts
            int ujj = tid & 7, ubb = tid >> 3;
            float g0 = gacc[ujj][ubb][0], g1 = gacc[ujj][ubb][1];
            float g2 = gacc[ujj][ubb][2], g3 = gacc[ujj][ubb][3];
            float2 hc = lstm_update(g0, g1, g2, g3, creg);
            creg = hc.y;
            int ub = (bg << 3) + ubb, ujh = (jg << 3) + ujj;
            agent_st(hbuf + (p ^ 1) * BH + ub * 512 + ujh, hc.x);
            seq_out[(size_t)(ub * SENC + t) * 512 + ujh] = hc.x;   // next-dispatch data
            if (t == SENC - 1) {
                hT[ub * 512 + ujh] = hc.x;
                cT[ub * 512 + ujh] = hc.y;
            }
        }
        ep++;
        grid_barrier_h(bar, xcd, ep);
        p ^= 1;
    }
}

// ---------------------------------------------------------------------------
// Decoder LSTM cell phase (device fn). Cross-block inputs via coherent x4
// loads, outputs via coherent stores; weights via normal (L2-resident) loads.
// ---------------------------------------------------------------------------
__device__ __forceinline__ void cell_phase(
    const float* __restrict__ Wih, const float* __restrict__ Whh,
    float bsum,
    const float* __restrict__ inp, const float* __restrict__ h_in,
    float* __restrict__ h_out, float* __restrict__ seqout,
    float& creg, int t, int jg, int bg, int row,
    float (*hs)[520], float (*is_)[520], float (*gacc)[8][5])
{
    int tid = threadIdx.x;
    {
        const float4* hsrc4 = (const float4*)(h_in + ((bg << 3) << 9));
        const float4* isrc4 = (const float4*)(inp + ((bg << 3) << 9));
        float4 hv4[4], iv4[4];
        #pragma unroll
        for (int u = 0; u < 4; u++) {
            hv4[u] = agent_ld4((const float*)(hsrc4 + tid + (u << 8)));
            iv4[u] = agent_ld4((const float*)(isrc4 + tid + (u << 8)));
        }
        asm volatile("s_waitcnt vmcnt(0)" ::: "memory");
        #pragma unroll
        for (int u = 0; u < 4; u++) {
            int d = (tid + (u << 8)) << 2;
            int rb = d >> 9, kk = d & 511;
            *(float4*)&hs[rb][kk] = hv4[u];
            *(float4*)&is_[rb][kk] = iv4[u];
        }
    }
    __syncthreads();
    int r = tid >> 3, bb = tid & 7;
    int g = r >> 3, jj = r & 7;
    const float* wi = Wih + (size_t)row * 512;
    const float* wh = Whh + (size_t)row * 512;
    const float* ir = is_[bb];
    const float* hr = hs[bb];
    float a0 = 0.f, a1 = 0.f, a2 = 0.f, a3 = 0.f;
    #pragma unroll 8
    for (int k = 0; k < 512; k += 4) {
        float4 wiv = *(const float4*)(wi + k);
        float4 iv = *(const float4*)(ir + k);
        float4 whv = *(const float4*)(wh + k);
        float4 hv = *(const float4*)(hr + k);
        a0 += wiv.x * iv.x + whv.x * hv.x;
        a1 += wiv.y * iv.y + whv.y * hv.y;
        a2 += wiv.z * iv.z + whv.z * hv.z;
        a3 += wiv.w * iv.w + whv.w * hv.w;
    }
    gacc[jj][bb][g] = bsum + (a0 + a1) + (a2 + a3);
    __syncthreads();
    if (tid < 64) {
        int ujj = tid & 7, ubb = tid >> 3;
        float g0 = gacc[ujj][ubb][0], g1 = gacc[ujj][ubb][1];
        float g2 = gacc[ujj][ubb][2], g3 = gacc[ujj][ubb][3];
        float2 hc = lstm_update(g0, g1, g2, g3, creg);
        creg = hc.y;
        int ub = (bg << 3) + ubb, ujh = (jg << 3) + ujj;
        agent_st(h_out + ub * 512 + ujh, hc.x);
        if (seqout) seqout[(size_t)(ub * SDEC + t) * 512 + ujh] = hc.x;  // next dispatch
    }
}

// ---------------------------------------------------------------------------
// Persistent decoder: all 32 timesteps, 5 barriers per step.
// Attention distributed across all 256 blocks, e-sliced by XCD so attn_W /
// comb_W slices stay L2-resident:
//   A1 (256 blk): hid[b, e-slice] = h2[b] @ attn_W[e-slice]^T
//   A2 (32 blk):  pw -> softmax -> ctx[b] (enc_out b-slices pinned per XCD)
//   A3 (256 blk): inp[b, e-slice] = tanh([xe|ctx] @ comb_W[e-slice]^T)
//   B, C: LSTM cells, jg row-groups pinned per XCD (2 MB weights/XCD).
// ---------------------------------------------------------------------------
__global__ __launch_bounds__(256) void decoder_persist(
    const int* __restrict__ xs, const float* __restrict__ yemb,
    const float* __restrict__ enc_out,
    const float* __restrict__ attn_W, const float* __restrict__ comb_W,
    const float* __restrict__ Wih0, const float* __restrict__ Whh0,
    const float* __restrict__ bih0, const float* __restrict__ bhh0,
    const float* __restrict__ Wih1, const float* __restrict__ Whh1,
    const float* __restrict__ bih1, const float* __restrict__ bhh1,
    const float* __restrict__ hT0, const float* __restrict__ cT0,
    const float* __restrict__ hT1, const float* __restrict__ cT1,
    float* __restrict__ dhb0, float* __restrict__ dhb1,
    float* __restrict__ inpbuf, float* __restrict__ h2seq,
    float* __restrict__ hidb, float* __restrict__ xcb,
    unsigned* __restrict__ bar)
{
    __shared__ __align__(16) float hs[8][520];
    __shared__ __align__(16) float is_[8][520];
    __shared__ float gacc[8][8][5];
    __shared__ __align__(16) float h2s[512];
    __shared__ __align__(16) float xcs[1024];
    __shared__ float pw[64];
    __shared__ float aw[64];
    int blk = blockIdx.x;
    int xcd = blk & 7, slot = blk >> 3;
    // cell role: XCD owns jg in [xcd*8, xcd*8+8)
    int jg = xcd * 8 + (slot >> 2), bg = slot & 3;
    // attention role: XCD owns e-slice [xcd*64, xcd*64+64); block handles b=slot
    int ab = slot;
    int e0 = xcd << 6;
    int tid = threadIdx.x;
    int lane = tid & 63, wv = tid >> 6;
    int r = tid >> 3;
    int g = r >> 3, jj = r & 7;
    int row = (g << 9) + (jg << 3) + jj;
    float bsum0 = bih0[row] + bhh0[row];
    float bsum1 = bih1[row] + bhh1[row];
    float c0 = 0.f, c1 = 0.f;
    if (tid < 64) {
        int ujj = tid & 7, ubb = tid >> 3;
        int ub = (bg << 3) + ubb, ujh = (jg << 3) + ujj;
        c0 = cT0[ub * 512 + ujh];
        c1 = cT1[ub * 512 + ujh];
    }
    unsigned ep = 0;
    int p = 0;
    for (int t = 0; t < SDEC; ++t) {
        int q = p ^ 1;
        // ---- A1: hid[ab, e0:e0+64) ----
        {
            const float* h2p = ((t == 0) ? hT1 : dhb1 + p * BH) + ab * 512;
            if (tid < 128) {
                float4 v = agent_ld4((const float*)((const float4*)h2p + tid));
                asm volatile("s_waitcnt vmcnt(0)" ::: "memory");
                ((float4*)h2s)[tid] = v;
            }
            __syncthreads();
            for (int e = wv; e < 64; e += 4) {
                const float* rowp = attn_W + (size_t)(e0 + e) * 512;
                float pp = 0.f;
                #pragma unroll
                for (int i = 0; i < 8; i++)
                    pp += h2s[lane + 64 * i] * rowp[lane + 64 * i];
                pp = allreduce64(pp);
                if (lane == 0) agent_st(hidb + ab * 512 + e0 + e, pp);
            }
        }
        ep++; grid_barrier_h(bar, xcd, ep);
        // ---- A2: pw/softmax/ctx for b = xcd*4 + slot (blocks 0..31) ----
        if (blk < 32) {
            int b = xcd * 4 + slot;    // 4 b per XCD -> enc_out slices resident
            if (tid < 128) {
                float4 v = agent_ld4((const float*)((const float4*)(hidb + b * 512) + tid));
                asm volatile("s_waitcnt vmcnt(0)" ::: "memory");
                ((float4*)h2s)[tid] = v;
            }
            __syncthreads();
            for (int s = wv; s < SENC; s += 4) {
                const float* rowp = enc_out + (size_t)(b * SENC + s) * 512;
                float pp = 0.f;
                #pragma unroll
                for (int i = 0; i < 8; i++)
                    pp += h2s[lane + 64 * i] * rowp[lane + 64 * i];
                pp = allreduce64(pp);
                if (lane == 0)
                    pw[s] = pp - ((xs[b * SENC + s] > 0) ? 0.f : 1e20f);
            }
            __syncthreads();
            if (tid < 64) {
                float v = pw[tid];
                float m = v;
                #pragma unroll
                for (int o = 1; o < 64; o <<= 1) m = fmaxf(m, __shfl_xor(m, o));
                float ex = expf(v - m);
                float sm = ex;
                #pragma unroll
                for (int o = 1; o < 64; o <<= 1) sm += __shfl_xor(sm, o);
                aw[tid] = ex / sm;
            }
            __syncthreads();
            for (int e = tid; e < 512; e += 256) {
                float s0 = 0.f, s1 = 0.f, s2 = 0.f, s3 = 0.f;
                #pragma unroll
                for (int ss = 0; ss < SENC; ss += 4) {
                    s0 += aw[ss + 0] * enc_out[(size_t)(b * SENC + ss + 0) * 512 + e];
                    s1 += aw[ss + 1] * enc_out[(size_t)(b * SENC + ss + 1) * 512 + e];
                    s2 += aw[ss + 2] * enc_out[(size_t)(b * SENC + ss + 2) * 512 + e];
                    s3 += aw[ss + 3] * enc_out[(size_t)(b * SENC + ss + 3) * 512 + e];
                }
                agent_st(xcb + b * 512 + e, (s0 + s1) + (s2 + s3));
            }
        }
        ep++; grid_barrier_h(bar, xcd, ep);
        // ---- A3: inp[ab, e0:e0+64) = tanh([xe|ctx] @ comb_W^T) ----
        {
            const float* yrow = yemb + (size_t)(ab * SDEC + t) * 512;  // read-only, cached
            if (tid < 128) {
                ((float4*)xcs)[tid] = *(const float4*)(yrow + (tid << 2));
            } else {
                int u = tid & 127;
                float4 c = agent_ld4((const float*)((const float4*)(xcb + (ab << 9)) + u));
                asm volatile("s_waitcnt vmcnt(0)" ::: "memory");
                ((float4*)(xcs + 512))[u] = c;
            }
            __syncthreads();
            for (int e = wv; e < 64; e += 4) {
                const float* rowp = comb_W + (size_t)(e0 + e) * 1024;
                float pp = 0.f;
                #pragma unroll
                for (int i = 0; i < 16; i++)
                    pp += xcs[lane + 64 * i] * rowp[lane + 64 * i];
                pp = allreduce64(pp);
                if (lane == 0) agent_st(inpbuf + ab * 512 + e0 + e, tanhf(pp));
            }
        }
        ep++; grid_barrier_h(bar, xcd, ep);
        // ---- B: layer-0 cell ----
        cell_phase(Wih0, Whh0, bsum0, inpbuf,
                   (t == 0) ? hT0 : dhb0 + p * BH, dhb0 + q * BH,
                   (float*)nullptr, c0, t, jg, bg, row, hs, is_, gacc);
        ep++; grid_barrier_h(bar, xcd, ep);
        // ---- C: layer-1 cell ----
        cell_phase(Wih1, Whh1, bsum1, dhb0 + q * BH,
                   (t == 0) ? hT1 : dhb1 + p * BH, dhb1 + q * BH,
                   h2seq, c1, t, jg, bg, row, hs, is_, gacc);
        ep++; grid_barrier_h(bar, xcd, ep);
        p = q;
    }
}

// ---------------------------------------------------------------------------
// argmax over scores[m, 1:], lowest index on ties; preds[m] = index (float)
// ---------------------------------------------------------------------------
__global__ __launch_bounds__(256) void argmax_kernel(const float* __restrict__ scores,
                                                     float* __restrict__ preds)
{
    __shared__ float sv[256];
    __shared__ int si[256];
    int m = blockIdx.x;
    const float* row = scores + (size_t)m * VDIM;
    float best = -3.4e38f;
    int bi = 0x7fffffff;
    for (int v = 1 + (int)threadIdx.x; v < VDIM; v += 256) {
        float val = row[v];
        if (val > best) { best = val; bi = v; }   // ascending scan → lowest idx kept
    }
    sv[threadIdx.x] = best;
    si[threadIdx.x] = bi;
    __syncthreads();
    for (int s = 128; s > 0; s >>= 1) {
        if ((int)threadIdx.x < s) {
            float ov = sv[threadIdx.x + s];
            int oi = si[threadIdx.x + s];
            if (ov > sv[threadIdx.x] ||
                (ov == sv[threadIdx.x] && oi < si[threadIdx.x])) {
                sv[threadIdx.x] = ov;
                si[threadIdx.x] = oi;
            }
        }
        __syncthreads();
    }
    if (threadIdx.x == 0) preds[m] = (float)si[0];
}

// ---------------------------------------------------------------------------
extern "C" void kernel_launch(void* const* d_in, const int* in_sizes, int n_in,
                              void* d_out, int out_size, void* d_ws, size_t ws_size,
                              hipStream_t stream)
{
    const int* xs = (const int*)d_in[0];
    const int* ys = (const int*)d_in[1];
    const float* emb = (const float*)d_in[2];
    const float* W[16];
    for (int i = 0; i < 16; i++) W[i] = (const float*)d_in[3 + i];
    // enc layer l: W[l*4+{0:Wih,1:Whh,2:bih,3:bhh}] ; dec layer l: W[8+l*4+...]
    const float* attn_W = (const float*)d_in[19];
    const float* comb_W = (const float*)d_in[20];
    float* out = (float*)d_out;
    float* ws = (float*)d_ws;

    // workspace layout (floats)
    float* xemb  = ws;                   // 2048*512      = 1,048,576
    float* xg    = xemb + 1048576;       // 2048*2048     = 4,194,304
    float* l0out = xg + 4194304;         // 2048*512
    float* l1out = l0out + 1048576;      // 2048*512  (enc_out)
    float* ench  = l1out + 1048576;      // 2*BH   (encoder h parity buffer)
    float* hT    = ench + 2 * BH;        // 2*BH   (final h per layer)
    float* cT    = hT + 2 * BH;          // 2*BH   (final c per layer)
    unsigned* barcnt = (unsigned*)(cT + 2 * BH);   // 3 x 1024 dwords
    // ys embeddings overlay xemb (dead after layer-0 pre-gate GEMM)
    float* yemb   = xemb;                // 1024*512 = 524,288
    // decoder buffers overlay xg (dead after encoder)
    float* h2seq  = xg;                  // 1024*512 = 524,288
    float* inpbuf = xg + 524288;         // BH
    float* dhb0   = inpbuf + BH;         // 2*BH parity
    float* dhb1   = dhb0 + 2 * BH;       // 2*BH parity
    float* hidb   = dhb1 + 2 * BH;       // BH
    float* xcb    = hidb + BH;           // BH (ctx only; xe read from yemb)

    hipMemsetAsync(barcnt, 0, 3 * 4096, stream);

    // ---- Encoder ----
    embed_kernel<<<B * SENC, 128, 0, stream>>>(xs, emb, xemb);
    for (int l = 0; l < 2; l++) {
        gemm_nt128<<<dim3(G4 / 128, (B * SENC) / 128), 256, 0, stream>>>(
            (l == 0) ? xemb : l0out, W[l * 4 + 0], xg,
            W[l * 4 + 2], W[l * 4 + 3], B * SENC, G4, 512);
        if (l == 0) {
            // xemb is dead now; fill ys embeddings into the same region
            embed_kernel<<<B * SDEC, 128, 0, stream>>>(ys, emb, yemb);
        }
        const float* xgp = xg;
        const float* whh = W[l * 4 + 1];
        float* seqo = (l == 0) ? l0out : l1out;
        float* hb = ench;
        float* hTl = hT + l * BH;
        float* cTl = cT + l * BH;
        unsigned* bp = barcnt + l * 1024;
        void* eargs[] = {(void*)&xgp, (void*)&whh, (void*)&seqo,
                         (void*)&hb, (void*)&hTl, (void*)&cTl, (void*)&bp};
        hipLaunchCooperativeKernel((void*)enc_layer_persist, dim3(NBLK), dim3(256),
                                   eargs, 0, stream);
    }

    // ---- Decoder (single persistent kernel, hierarchical barriers) ----
    {
        const int* xs_ = xs;
        const float* yemb_ = yemb;
        const float* enc_out_ = l1out;
        const float* attnW_ = attn_W;
        const float* combW_ = comb_W;
        const float* wih0 = W[8];
        const float* whh0 = W[9];
        const float* bih0 = W[10];
        const float* bhh0 = W[11];
        const float* wih1 = W[12];
        const float* whh1 = W[13];
        const float* bih1 = W[14];
        const float* bhh1 = W[15];
        const float* hT0_ = hT;
        const float* cT0_ = cT;
        const float* hT1_ = hT + BH;
        const float* cT1_ = cT + BH;
        float* dhb0_ = dhb0;
        float* dhb1_ = dhb1;
        float* inp_ = inpbuf;
        float* h2seq_ = h2seq;
        float* hidb_ = hidb;
        float* xcb_ = xcb;
        unsigned* bp = barcnt + 2 * 1024;
        void* dargs[] = {(void*)&xs_, (void*)&yemb_, (void*)&enc_out_,
                         (void*)&attnW_, (void*)&combW_,
                         (void*)&wih0, (void*)&whh0, (void*)&bih0, (void*)&bhh0,
                         (void*)&wih1, (void*)&whh1, (void*)&bih1, (void*)&bhh1,
                         (void*)&hT0_, (void*)&cT0_, (void*)&hT1_, (void*)&cT1_,
                         (void*)&dhb0_, (void*)&dhb1_, (void*)&inp_, (void*)&h2seq_,
                         (void*)&hidb_, (void*)&xcb_, (void*)&bp};
        hipLaunchCooperativeKernel((void*)decoder_persist, dim3(NBLK), dim3(256),
                                   dargs, 0, stream);
    }

    // ---- Output projection + argmax ----
    gemm_nt128<<<dim3(VDIM / 128, (B * SDEC) / 128), 256, 0, stream>>>(
        h2seq, emb, out + B * SDEC, nullptr, nullptr, B * SDEC, VDIM, 512);
    argmax_kernel<<<B * SDEC, 256, 0, stream>>>(out + B * SDEC, out);
}

// Round 5
// 3622.594 us; speedup vs baseline: 3.9218x; 1.2291x over previous
//
#include <hip/hip_runtime.h>
#include <math.h>

// Problem constants
#define B 32
#define SENC 64
#define SDEC 32
#define HDIM 512
#define EDIM 512
#define VDIM 32000
#define G4 2048              // 4*H
#define BH (B*HDIM)          // 16384
#define NBLK 256

// ---------------------------------------------------------------------------
// Coherent (cross-XCD) accessors. sc0 sc1 = system scope (bypasses L1+L2).
// Read-only weights use normal loads -> stay L2-cached.
// ---------------------------------------------------------------------------
__device__ __forceinline__ void agent_st(float* p, float v)
{
    __hip_atomic_store(p, v, __ATOMIC_RELAXED, __HIP_MEMORY_SCOPE_AGENT);
}
// Issue-only vector coherent load: caller MUST execute
// asm volatile("s_waitcnt vmcnt(0)" ::: "memory") before using the result.
__device__ __forceinline__ float4 agent_ld4(const float* p)
{
    float4 v;
    asm volatile("global_load_dwordx4 %0, %1, off sc0 sc1"
                 : "=v"(v) : "v"(p) : "memory");
    return v;
}

// ---------------------------------------------------------------------------
// Hierarchical grid barrier (256 blocks = 8 XCD-groups x 32).
// Monotonic epochs -> no resets. vmcnt(0) drains coherent stores first.
// ---------------------------------------------------------------------------
__device__ __forceinline__ void grid_barrier_h(unsigned* bar, int xcd, unsigned ep)
{
    asm volatile("s_waitcnt vmcnt(0) lgkmcnt(0)" ::: "memory");
    __syncthreads();
    if (threadIdx.x == 0) {
        unsigned* xcnt = bar + xcd * 16;
        unsigned* gcnt = bar + 256;
        unsigned* rfl  = bar + 512 + xcd * 16;
        unsigned prev = __hip_atomic_fetch_add(xcnt, 1u, __ATOMIC_RELAXED,
                                               __HIP_MEMORY_SCOPE_AGENT);
        if (prev == ep * 32u - 1u) {
            __hip_atomic_fetch_add(gcnt, 1u, __ATOMIC_RELAXED,
                                   __HIP_MEMORY_SCOPE_AGENT);
            while (__hip_atomic_load(gcnt, __ATOMIC_RELAXED,
                                     __HIP_MEMORY_SCOPE_AGENT) < ep * 8u)
                __builtin_amdgcn_s_sleep(1);
            __hip_atomic_store(rfl, ep, __ATOMIC_RELAXED,
                               __HIP_MEMORY_SCOPE_AGENT);
        } else {
            while (__hip_atomic_load(rfl, __ATOMIC_RELAXED,
                                     __HIP_MEMORY_SCOPE_AGENT) < ep)
                __builtin_amdgcn_s_sleep(2);
        }
        asm volatile("" ::: "memory");
    }
    __syncthreads();
}

// ---------------------------------------------------------------------------
// embed: gather emb rows for a token sequence  (n_tok blocks x 128 threads)
// ---------------------------------------------------------------------------
__global__ __launch_bounds__(128) void embed_kernel(const int* __restrict__ toks,
                                                    const float* __restrict__ emb,
                                                    float* __restrict__ out)
{
    int t = blockIdx.x;
    int id = toks[t];
    const float4* src = (const float4*)(emb + (size_t)id * EDIM);
    float4* dst = (float4*)(out + (size_t)t * EDIM);
    dst[threadIdx.x] = src[threadIdx.x];   // 128 * float4 = 512 floats
}

// ---------------------------------------------------------------------------
// NT SGEMM: C[m,n] = sum_k A[m*K+k]*B[n*ldb+k] (+bias0[n]+bias1[n])
// block tile 128x128, 256 threads, 8x8 microtile.
// ---------------------------------------------------------------------------
__global__ __launch_bounds__(256) void gemm_nt128(const float* __restrict__ A,
                                                  const float* __restrict__ Bm,
                                                  float* __restrict__ C,
                                                  const float* __restrict__ bias0,
                                                  const float* __restrict__ bias1,
                                                  int M, int N, int K, int ldb)
{
    __shared__ float As[16][128];
    __shared__ float Bs[16][128];
    int tid = threadIdx.x;
    int tx = tid & 15, ty = tid >> 4;            // 16 x 16 thread grid
    int m0 = blockIdx.y * 128, n0 = blockIdx.x * 128;

    float acc[8][8];
    #pragma unroll
    for (int i = 0; i < 8; i++)
        #pragma unroll
        for (int j = 0; j < 8; j++) acc[i][j] = 0.f;

    int lr = tid >> 1, lk = (tid & 1) * 8;       // row 0..127, k 0 or 8
    const float* Aptr = A + (size_t)(m0 + lr) * K + lk;
    const float* Bptr = Bm + (size_t)(n0 + lr) * ldb + lk;

    for (int k0 = 0; k0 < K; k0 += 16) {
        float4 a1 = *(const float4*)(Aptr + k0);
        float4 a2 = *(const float4*)(Aptr + k0 + 4);
        float4 b1 = *(const float4*)(Bptr + k0);
        float4 b2 = *(const float4*)(Bptr + k0 + 4);
        As[lk + 0][lr] = a1.x; As[lk + 1][lr] = a1.y;
        As[lk + 2][lr] = a1.z; As[lk + 3][lr] = a1.w;
        As[lk + 4][lr] = a2.x; As[lk + 5][lr] = a2.y;
        As[lk + 6][lr] = a2.z; As[lk + 7][lr] = a2.w;
        Bs[lk + 0][lr] = b1.x; Bs[lk + 1][lr] = b1.y;
        Bs[lk + 2][lr] = b1.z; Bs[lk + 3][lr] = b1.w;
        Bs[lk + 4][lr] = b2.x; Bs[lk + 5][lr] = b2.y;
        Bs[lk + 6][lr] = b2.z; Bs[lk + 7][lr] = b2.w;
        __syncthreads();
        #pragma unroll
        for (int kk = 0; kk < 16; kk++) {
            float4 av1 = *(const float4*)&As[kk][ty * 8];
            float4 av2 = *(const float4*)&As[kk][ty * 8 + 4];
            float4 bv1 = *(const float4*)&Bs[kk][tx * 8];
            float4 bv2 = *(const float4*)&Bs[kk][tx * 8 + 4];
            float am[8] = {av1.x, av1.y, av1.z, av1.w, av2.x, av2.y, av2.z, av2.w};
            float bn[8] = {bv1.x, bv1.y, bv1.z, bv1.w, bv2.x, bv2.y, bv2.z, bv2.w};
            #pragma unroll
            for (int i = 0; i < 8; i++)
                #pragma unroll
                for (int j = 0; j < 8; j++)
                    acc[i][j] += am[i] * bn[j];
        }
        __syncthreads();
    }

    int nc = n0 + tx * 8;
    float bb[8];
    #pragma unroll
    for (int j = 0; j < 8; j++) {
        bb[j] = 0.f;
        if (bias0) bb[j] += bias0[nc + j];
        if (bias1) bb[j] += bias1[nc + j];
    }
    #pragma unroll
    for (int i = 0; i < 8; i++) {
        int row = m0 + ty * 8 + i;
        float4 o1 = make_float4(acc[i][0] + bb[0], acc[i][1] + bb[1],
                                acc[i][2] + bb[2], acc[i][3] + bb[3]);
        float4 o2 = make_float4(acc[i][4] + bb[4], acc[i][5] + bb[5],
                                acc[i][6] + bb[6], acc[i][7] + bb[7]);
        *(float4*)(C + (size_t)row * N + nc) = o1;
        *(float4*)(C + (size_t)row * N + nc + 4) = o2;
    }
}

// ---------------------------------------------------------------------------
// NN SGEMM: C[m,n] = sum_k A[m*K+k]*B[k*N+n]  (for encT = enc_out @ attn_W)
// ---------------------------------------------------------------------------
__global__ __launch_bounds__(256) void gemm_nn128(const float* __restrict__ A,
                                                  const float* __restrict__ Bm,
                                                  float* __restrict__ C,
                                                  int M, int N, int K)
{
    __shared__ float As[16][128];
    __shared__ float Bs[16][128];
    int tid = threadIdx.x;
    int tx = tid & 15, ty = tid >> 4;
    int m0 = blockIdx.y * 128, n0 = blockIdx.x * 128;

    float acc[8][8];
    #pragma unroll
    for (int i = 0; i < 8; i++)
        #pragma unroll
        for (int j = 0; j < 8; j++) acc[i][j] = 0.f;

    int lr = tid >> 1, lk = (tid & 1) * 8;
    const float* Aptr = A + (size_t)(m0 + lr) * K + lk;
    int bk = tid >> 5;                // 0..7
    int bn = (tid & 31) << 2;         // 0..124

    for (int k0 = 0; k0 < K; k0 += 16) {
        float4 a1 = *(const float4*)(Aptr + k0);
        float4 a2 = *(const float4*)(Aptr + k0 + 4);
        float4 v1 = *(const float4*)(Bm + (size_t)(k0 + bk) * N + n0 + bn);
        float4 v2 = *(const float4*)(Bm + (size_t)(k0 + bk + 8) * N + n0 + bn);
        As[lk + 0][lr] = a1.x; As[lk + 1][lr] = a1.y;
        As[lk + 2][lr] = a1.z; As[lk + 3][lr] = a1.w;
        As[lk + 4][lr] = a2.x; As[lk + 5][lr] = a2.y;
        As[lk + 6][lr] = a2.z; As[lk + 7][lr] = a2.w;
        *(float4*)&Bs[bk][bn] = v1;
        *(float4*)&Bs[bk + 8][bn] = v2;
        __syncthreads();
        #pragma unroll
        for (int kk = 0; kk < 16; kk++) {
            float4 av1 = *(const float4*)&As[kk][ty * 8];
            float4 av2 = *(const float4*)&As[kk][ty * 8 + 4];
            float4 bv1 = *(const float4*)&Bs[kk][tx * 8];
            float4 bv2 = *(const float4*)&Bs[kk][tx * 8 + 4];
            float am[8] = {av1.x, av1.y, av1.z, av1.w, av2.x, av2.y, av2.z, av2.w};
            float bv[8] = {bv1.x, bv1.y, bv1.z, bv1.w, bv2.x, bv2.y, bv2.z, bv2.w};
            #pragma unroll
            for (int i = 0; i < 8; i++)
                #pragma unroll
                for (int j = 0; j < 8; j++)
                    acc[i][j] += am[i] * bv[j];
        }
        __syncthreads();
    }

    int nc = n0 + tx * 8;
    #pragma unroll
    for (int i = 0; i < 8; i++) {
        int row = m0 + ty * 8 + i;
        float4 o1 = make_float4(acc[i][0], acc[i][1], acc[i][2], acc[i][3]);
        float4 o2 = make_float4(acc[i][4], acc[i][5], acc[i][6], acc[i][7]);
        *(float4*)(C + (size_t)row * N + nc) = o1;
        *(float4*)(C + (size_t)row * N + nc + 4) = o2;
    }
}

// ---------------------------------------------------------------------------
// helpers
// ---------------------------------------------------------------------------
__device__ __forceinline__ float allreduce64(float v)
{
    #pragma unroll
    for (int m = 1; m < 64; m <<= 1) v += __shfl_xor(v, m);
    return v;
}

__device__ __forceinline__ float2 lstm_update(float i_, float f_, float g_,
                                              float o_, float c)
{
    float ig = 1.f / (1.f + expf(-i_));
    float fg = 1.f / (1.f + expf(-f_));
    float gg = tanhf(g_);
    float og = 1.f / (1.f + expf(-o_));
    float cn = fg * c + ig * gg;
    float hn = og * tanhf(cn);
    return make_float2(hn, cn);
}

// ---------------------------------------------------------------------------
// Fused 2-layer encoder as a time-pipeline. 65 macro-steps, 1 barrier each.
// Blocks: xcd = blk&7, slot = blk>>3. role = slot>>4 (0: layer0, 1: layer1).
// s2 = slot&15: jgroup = xcd*8 + (s2>>1) (weights XCD-pinned), bg2 = s2&1
// (16 batch rows per block; thread handles b and b+8).
// Layer0 at step u computes t=u using precomputed xg; layer1 at u computes
// t=u-1 with Wih1@h0(t) + Whh1@h1(t-1) on the fly (no pre-gate GEMM).
// c state in registers of tid<128; h exchanged via coherent parity buffers.
// ---------------------------------------------------------------------------
__global__ __launch_bounds__(256) void enc_fused(
    const float* __restrict__ xg, const float* __restrict__ Whh0,
    const float* __restrict__ Wih1, const float* __restrict__ Whh1,
    const float* __restrict__ bih1, const float* __restrict__ bhh1,
    float* __restrict__ l1out, float* __restrict__ h0buf,
    float* __restrict__ h1buf, float* __restrict__ hT, float* __restrict__ cT,
    unsigned* __restrict__ bar)
{
    __shared__ __align__(16) float hs[16][520];
    __shared__ __align__(16) float is_[16][520];
    __shared__ float gacc[8][16][5];
    int blk = blockIdx.x;
    int xcd = blk & 7, slot = blk >> 3;
    int role = slot >> 4;
    int s2 = slot & 15;
    int jgroup = xcd * 8 + (s2 >> 1);        // [0,64)
    int bg2 = s2 & 1;
    int tid = threadIdx.x;
    int r = tid >> 3, bb = tid & 7;
    int g = r >> 3, jj = r & 7;
    int row = (g << 9) + (jgroup << 3) + jj; // gate-row in [0,2048)
    int b0 = (bg2 << 4) + bb;
    const float* w0 = role ? (Wih1 + (size_t)row * 512)
                           : (Whh0 + (size_t)row * 512);
    const float* w1 = role ? (Whh1 + (size_t)row * 512) : (const float*)0;
    float bsum = role ? (bih1[row] + bhh1[row]) : 0.f;
    float creg = 0.f;
    unsigned ep = 0;
    int p = 0;
    for (int u = 0; u <= SENC; ++u) {
        int active = role ? (u >= 1) : (u < SENC);
        int t = role ? (u - 1) : u;
        if (active) {
            // ---- stage inputs into LDS ----
            if (!role) {
                if (t == 0) {
                    float4 z = make_float4(0.f, 0.f, 0.f, 0.f);
                    #pragma unroll
                    for (int v = 0; v < 8; v++) {
                        int d = (tid + (v << 8)) << 2;
                        *(float4*)&hs[d >> 9][d & 511] = z;
                    }
                } else {
                    const float4* s4 = (const float4*)(h0buf + p * BH + ((bg2 << 4) << 9));
                    float4 hv[8];
                    #pragma unroll
                    for (int v = 0; v < 8; v++)
                        hv[v] = agent_ld4((const float*)(s4 + tid + (v << 8)));
                    asm volatile("s_waitcnt vmcnt(0)" ::: "memory");
                    #pragma unroll
                    for (int v = 0; v < 8; v++) {
                        int d = (tid + (v << 8)) << 2;
                        *(float4*)&hs[d >> 9][d & 511] = hv[v];
                    }
                }
            } else {
                const float4* s40 = (const float4*)(h0buf + p * BH + ((bg2 << 4) << 9));
                float4 hv[8];
                #pragma unroll
                for (int v = 0; v < 8; v++)
                    hv[v] = agent_ld4((const float*)(s40 + tid + (v << 8)));
                if (t == 0) {
                    asm volatile("s_waitcnt vmcnt(0)" ::: "memory");
                    float4 z = make_float4(0.f, 0.f, 0.f, 0.f);
                    #pragma unroll
                    for (int v = 0; v < 8; v++) {
                        int d = (tid + (v << 8)) << 2;
                        *(float4*)&hs[d >> 9][d & 511] = hv[v];
                        *(float4*)&is_[d >> 9][d & 511] = z;
                    }
                } else {
                    const float4* s41 = (const float4*)(h1buf + p * BH + ((bg2 << 4) << 9));
                    float4 iv[8];
                    #pragma unroll
                    for (int v = 0; v < 8; v++)
                        iv[v] = agent_ld4((const float*)(s41 + tid + (v << 8)));
                    asm volatile("s_waitcnt vmcnt(0)" ::: "memory");
                    #pragma unroll
                    for (int v = 0; v < 8; v++) {
                        int d = (tid + (v << 8)) << 2;
                        *(float4*)&hs[d >> 9][d & 511] = hv[v];
                        *(float4*)&is_[d >> 9][d & 511] = iv[v];
                    }
                }
            }
            __syncthreads();
            // ---- gates for (b0) and (b0+8) ----
            float acc0, acc1;
            if (!role) {
                acc0 = xg[(size_t)(b0 * SENC + t) * G4 + row];
                acc1 = xg[(size_t)((b0 + 8) * SENC + t) * G4 + row];
                float a00 = 0, a01 = 0, a02 = 0, a03 = 0;
                float a10 = 0, a11 = 0, a12 = 0, a13 = 0;
                const float* ha = hs[bb];
                const float* hb = hs[bb + 8];
                #pragma unroll 4
                for (int k = 0; k < 512; k += 4) {
                    float4 w = *(const float4*)(w0 + k);
                    float4 x = *(const float4*)(ha + k);
                    float4 y = *(const float4*)(hb + k);
                    a00 += w.x * x.x; a01 += w.y * x.y;
                    a02 += w.z * x.z; a03 += w.w * x.w;
                    a10 += w.x * y.x; a11 += w.y * y.y;
                    a12 += w.z * y.z; a13 += w.w * y.w;
                }
                acc0 += (a00 + a01) + (a02 + a03);
                acc1 += (a10 + a11) + (a12 + a13);
            } else {
                float a00 = 0, a01 = 0, a02 = 0, a03 = 0;
                float a10 = 0, a11 = 0, a12 = 0, a13 = 0;
                const float* h0a = hs[bb];
                const float* h0b = hs[bb + 8];
                const float* h1a = is_[bb];
                const float* h1b = is_[bb + 8];
                #pragma unroll 2
                for (int k = 0; k < 512; k += 4) {
                    float4 wi = *(const float4*)(w0 + k);
                    float4 wh = *(const float4*)(w1 + k);
                    float4 xa = *(const float4*)(h0a + k);
                    float4 xb = *(const float4*)(h0b + k);
                    float4 ya = *(const float4*)(h1a + k);
                    float4 yb = *(const float4*)(h1b + k);
                    a00 += wi.x * xa.x + wh.x * ya.x;
                    a01 += wi.y * xa.y + wh.y * ya.y;
                    a02 += wi.z * xa.z + wh.z * ya.z;
                    a03 += wi.w * xa.w + wh.w * ya.w;
                    a10 += wi.x * xb.x + wh.x * yb.x;
                    a11 += wi.y * xb.y + wh.y * yb.y;
                    a12 += wi.z * xb.z + wh.z * yb.z;
                    a13 += wi.w * xb.w + wh.w * yb.w;
                }
                acc0 = bsum + (a00 + a01) + (a02 + a03);
                acc1 = bsum + (a10 + a11) + (a12 + a13);
            }
            gacc[jj][bb][g] = acc0;
            gacc[jj][bb + 8][g] = acc1;
            __syncthreads();
            // ---- LSTM update (tid<128: one (b,jh) cell each) ----
            if (tid < 128) {
                int ujj = tid & 7, ulb = tid >> 3;    // ulb 0..15
                float g0 = gacc[ujj][ulb][0], g1 = gacc[ujj][ulb][1];
                float g2 = gacc[ujj][ulb][2], g3 = gacc[ujj][ulb][3];
                float2 hc = lstm_update(g0, g1, g2, g3, creg);
                creg = hc.y;
                int ub = (bg2 << 4) + ulb;
                int ujh = (jgroup << 3) + ujj;
                if (!role) {
                    agent_st(h0buf + (p ^ 1) * BH + ub * 512 + ujh, hc.x);
                    if (t == SENC - 1) {
                        hT[ub * 512 + ujh] = hc.x;
                        cT[ub * 512 + ujh] = hc.y;
                    }
                } else {
                    agent_st(h1buf + (p ^ 1) * BH + ub * 512 + ujh, hc.x);
                    l1out[(size_t)(ub * SENC + t) * 512 + ujh] = hc.x;
                    if (t == SENC - 1) {
                        hT[BH + ub * 512 + ujh] = hc.x;
                        cT[BH + ub * 512 + ujh] = hc.y;
                    }
                }
            }
        }
        ep++;
        grid_barrier_h(bar, xcd, ep);
        p ^= 1;
    }
}

// ---------------------------------------------------------------------------
// Decoder LSTM cell phase (device fn). Coherent x4 staging; L2 weights.
// ---------------------------------------------------------------------------
__device__ __forceinline__ void cell_phase(
    const float* __restrict__ Wih, const float* __restrict__ Whh,
    float bsum,
    const float* __restrict__ inp, const float* __restrict__ h_in,
    float* __restrict__ h_out, float* __restrict__ seqout,
    float& creg, int t, int jg, int bg, int row,
    float (*hs)[520], float (*is_)[520], float (*gacc)[8][5])
{
    int tid = threadIdx.x;
    {
        const float4* hsrc4 = (const float4*)(h_in + ((bg << 3) << 9));
        const float4* isrc4 = (const float4*)(inp + ((bg << 3) << 9));
        float4 hv4[4], iv4[4];
        #pragma unroll
        for (int u = 0; u < 4; u++) {
            hv4[u] = agent_ld4((const float*)(hsrc4 + tid + (u << 8)));
            iv4[u] = agent_ld4((const float*)(isrc4 + tid + (u << 8)));
        }
        asm volatile("s_waitcnt vmcnt(0)" ::: "memory");
        #pragma unroll
        for (int u = 0; u < 4; u++) {
            int d = (tid + (u << 8)) << 2;
            int rb = d >> 9, kk = d & 511;
            *(float4*)&hs[rb][kk] = hv4[u];
            *(float4*)&is_[rb][kk] = iv4[u];
        }
    }
    __syncthreads();
    int r = tid >> 3, bb = tid & 7;
    int g = r >> 3, jj = r & 7;
    const float* wi = Wih + (size_t)row * 512;
    const float* wh = Whh + (size_t)row * 512;
    const float* ir = is_[bb];
    const float* hr = hs[bb];
    float a0 = 0.f, a1 = 0.f, a2 = 0.f, a3 = 0.f;
    #pragma unroll 8
    for (int k = 0; k < 512; k += 4) {
        float4 wiv = *(const float4*)(wi + k);
        float4 iv = *(const float4*)(ir + k);
        float4 whv = *(const float4*)(wh + k);
        float4 hv = *(const float4*)(hr + k);
        a0 += wiv.x * iv.x + whv.x * hv.x;
        a1 += wiv.y * iv.y + whv.y * hv.y;
        a2 += wiv.z * iv.z + whv.z * hv.z;
        a3 += wiv.w * iv.w + whv.w * hv.w;
    }
    gacc[jj][bb][g] = bsum + (a0 + a1) + (a2 + a3);
    __syncthreads();
    if (tid < 64) {
        int ujj = tid & 7, ubb = tid >> 3;
        float g0 = gacc[ujj][ubb][0], g1 = gacc[ujj][ubb][1];
        float g2 = gacc[ujj][ubb][2], g3 = gacc[ujj][ubb][3];
        float2 hc = lstm_update(g0, g1, g2, g3, creg);
        creg = hc.y;
        int ub = (bg << 3) + ubb, ujh = (jg << 3) + ujj;
        agent_st(h_out + ub * 512 + ujh, hc.x);
        if (seqout) seqout[(size_t)(ub * SDEC + t) * 512 + ujh] = hc.x;
    }
}

// ---------------------------------------------------------------------------
// Persistent decoder: 32 timesteps x 3 barriers (minimum for the serial
// chain attn -> cell0 -> cell1).
// Phase A (all 256 blocks): b = xcd*4+(slot>>3), e0 = (slot&7)*64.
//   pw[s] = h2 . encT[b,s] (attn_W pre-applied), softmax, ctx (redundant
//   per-b across 8 e-slice blocks, deterministic), then
//   inp[b,e0:e0+64) = tanh(yg[b,t,e] + ctx @ Wc[e]) coherent-stored.
// Phases B/C: LSTM cells, weight rows XCD-pinned.
// ---------------------------------------------------------------------------
__global__ __launch_bounds__(256) void decoder_persist(
    const int* __restrict__ xs,
    const float* __restrict__ enc_out, const float* __restrict__ encT,
    const float* __restrict__ yg, const float* __restrict__ comb_W,
    const float* __restrict__ Wih0, const float* __restrict__ Whh0,
    const float* __restrict__ bih0, const float* __restrict__ bhh0,
    const float* __restrict__ Wih1, const float* __restrict__ Whh1,
    const float* __restrict__ bih1, const float* __restrict__ bhh1,
    const float* __restrict__ hT0, const float* __restrict__ cT0,
    const float* __restrict__ hT1, const float* __restrict__ cT1,
    float* __restrict__ dhb0, float* __restrict__ dhb1,
    float* __restrict__ inpbuf, float* __restrict__ h2seq,
    unsigned* __restrict__ bar)
{
    __shared__ __align__(16) float hs[8][520];
    __shared__ __align__(16) float is_[8][520];
    __shared__ float gacc[8][8][5];
    __shared__ __align__(16) float h2s[512];
    __shared__ __align__(16) float ctxs[512];
    __shared__ float pw[64];
    __shared__ float aw[64];
    int blk = blockIdx.x;
    int xcd = blk & 7, slot = blk >> 3;
    int jg = xcd * 8 + (slot >> 2), bg = slot & 3;    // cell role
    int ab = xcd * 4 + (slot >> 3);                   // attention b (XCD-pinned)
    int e0 = (slot & 7) << 6;                         // attention e-slice
    int tid = threadIdx.x;
    int lane = tid & 63, wv = tid >> 6;
    int r = tid >> 3;
    int g = r >> 3, jj = r & 7;
    int row = (g << 9) + (jg << 3) + jj;
    float bsum0 = bih0[row] + bhh0[row];
    float bsum1 = bih1[row] + bhh1[row];
    float c0 = 0.f, c1 = 0.f;
    if (tid < 64) {
        int ujj = tid & 7, ubb = tid >> 3;
        int ub = (bg << 3) + ubb, ujh = (jg << 3) + ujj;
        c0 = cT0[ub * 512 + ujh];
        c1 = cT1[ub * 512 + ujh];
    }
    unsigned ep = 0;
    int p = 0;
    for (int t = 0; t < SDEC; ++t) {
        int q = p ^ 1;
        // ---- Phase A: attention + combine ----
        {
            const float* h2p = ((t == 0) ? hT1 : dhb1 + p * BH) + ab * 512;
            if (tid < 128) {
                float4 v = agent_ld4((const float*)((const float4*)h2p + tid));
                asm volatile("s_waitcnt vmcnt(0)" ::: "memory");
                ((float4*)h2s)[tid] = v;
            }
            __syncthreads();
            // pw[s] = h2 . encT[ab,s] - neg
            for (int s = wv; s < SENC; s += 4) {
                const float* rowp = encT + (size_t)(ab * SENC + s) * 512;
                float pp = 0.f;
                #pragma unroll
                for (int i = 0; i < 8; i++)
                    pp += h2s[lane + 64 * i] * rowp[lane + 64 * i];
                pp = allreduce64(pp);
                if (lane == 0)
                    pw[s] = pp - ((xs[ab * SENC + s] > 0) ? 0.f : 1e20f);
            }
            __syncthreads();
            if (tid < 64) {
                float v = pw[tid];
                float m = v;
                #pragma unroll
                for (int o = 1; o < 64; o <<= 1) m = fmaxf(m, __shfl_xor(m, o));
                float ex = expf(v - m);
                float sm = ex;
                #pragma unroll
                for (int o = 1; o < 64; o <<= 1) sm += __shfl_xor(sm, o);
                aw[tid] = ex / sm;
            }
            __syncthreads();
            // ctx (full 512, redundant across e-slice blocks of same b)
            for (int e = tid; e < 512; e += 256) {
                float s0 = 0.f, s1 = 0.f, s2 = 0.f, s3 = 0.f;
                #pragma unroll
                for (int ss = 0; ss < SENC; ss += 4) {
                    s0 += aw[ss + 0] * enc_out[(size_t)(ab * SENC + ss + 0) * 512 + e];
                    s1 += aw[ss + 1] * enc_out[(size_t)(ab * SENC + ss + 1) * 512 + e];
                    s2 += aw[ss + 2] * enc_out[(size_t)(ab * SENC + ss + 2) * 512 + e];
                    s3 += aw[ss + 3] * enc_out[(size_t)(ab * SENC + ss + 3) * 512 + e];
                }
                ctxs[e] = (s0 + s1) + (s2 + s3);
            }
            __syncthreads();
            // inp slice: tanh(yg + ctx @ Wc^T)
            for (int e = wv; e < 64; e += 4) {
                const float* rowp = comb_W + (size_t)(e0 + e) * 1024 + 512;
                float pp = 0.f;
                #pragma unroll
                for (int i = 0; i < 8; i++)
                    pp += ctxs[lane + 64 * i] * rowp[lane + 64 * i];
                pp = allreduce64(pp);
                if (lane == 0)
                    agent_st(inpbuf + ab * 512 + e0 + e,
                             tanhf(yg[(size_t)(ab * SDEC + t) * 512 + e0 + e] + pp));
            }
        }
        ep++; grid_barrier_h(bar, xcd, ep);
        // ---- Phase B: layer-0 cell ----
        cell_phase(Wih0, Whh0, bsum0, inpbuf,
                   (t == 0) ? hT0 : dhb0 + p * BH, dhb0 + q * BH,
                   (float*)nullptr, c0, t, jg, bg, row, hs, is_, gacc);
        ep++; grid_barrier_h(bar, xcd, ep);
        // ---- Phase C: layer-1 cell ----
        cell_phase(Wih1, Whh1, bsum1, dhb0 + q * BH,
                   (t == 0) ? hT1 : dhb1 + p * BH, dhb1 + q * BH,
                   h2seq, c1, t, jg, bg, row, hs, is_, gacc);
        ep++; grid_barrier_h(bar, xcd, ep);
        p = q;
    }
}

// ---------------------------------------------------------------------------
// argmax over scores[m, 1:], lowest index on ties; preds[m] = index (float)
// ---------------------------------------------------------------------------
__global__ __launch_bounds__(256) void argmax_kernel(const float* __restrict__ scores,
                                                     float* __restrict__ preds)
{
    __shared__ float sv[256];
    __shared__ int si[256];
    int m = blockIdx.x;
    const float* row = scores + (size_t)m * VDIM;
    float best = -3.4e38f;
    int bi = 0x7fffffff;
    for (int v = 1 + (int)threadIdx.x; v < VDIM; v += 256) {
        float val = row[v];
        if (val > best) { best = val; bi = v; }   // ascending scan → lowest idx kept
    }
    sv[threadIdx.x] = best;
    si[threadIdx.x] = bi;
    __syncthreads();
    for (int s = 128; s > 0; s >>= 1) {
        if ((int)threadIdx.x < s) {
            float ov = sv[threadIdx.x + s];
            int oi = si[threadIdx.x + s];
            if (ov > sv[threadIdx.x] ||
                (ov == sv[threadIdx.x] && oi < si[threadIdx.x])) {
                sv[threadIdx.x] = ov;
                si[threadIdx.x] = oi;
            }
        }
        __syncthreads();
    }
    if (threadIdx.x == 0) preds[m] = (float)si[0];
}

// ---------------------------------------------------------------------------
extern "C" void kernel_launch(void* const* d_in, const int* in_sizes, int n_in,
                              void* d_out, int out_size, void* d_ws, size_t ws_size,
                              hipStream_t stream)
{
    const int* xs = (const int*)d_in[0];
    const int* ys = (const int*)d_in[1];
    const float* emb = (const float*)d_in[2];
    const float* W[16];
    for (int i = 0; i < 16; i++) W[i] = (const float*)d_in[3 + i];
    // enc layer l: W[l*4+{0:Wih,1:Whh,2:bih,3:bhh}] ; dec layer l: W[8+l*4+...]
    const float* attn_W = (const float*)d_in[19];
    const float* comb_W = (const float*)d_in[20];
    float* out = (float*)d_out;
    float* ws = (float*)d_ws;

    // workspace layout (floats)
    float* xemb   = ws;                    // 2048*512
    float* xg     = xemb + 1048576;        // 2048*2048 (layer-0 pre-gates)
    float* l1out  = xg + 4194304;          // 2048*512  (enc_out)
    float* encT   = l1out + 1048576;       // 2048*512  (enc_out @ attn_W)
    float* h0buf  = encT + 1048576;        // 2*BH
    float* h1buf  = h0buf + 2 * BH;        // 2*BH
    float* hT     = h1buf + 2 * BH;        // 2*BH (layer0 | layer1)
    float* cT     = hT + 2 * BH;           // 2*BH
    unsigned* barcnt = (unsigned*)(cT + 2 * BH);   // 2 x 1024 dwords
    // ys embeddings overlay xemb (dead after layer-0 pre-gate GEMM)
    float* yemb   = xemb;                  // 1024*512
    // decoder buffers overlay xg (dead after encoder)
    float* h2seq  = xg;                    // 1024*512
    float* inpbuf = xg + 524288;           // BH
    float* dhb0   = inpbuf + BH;           // 2*BH parity
    float* dhb1   = dhb0 + 2 * BH;         // 2*BH parity
    float* yg     = dhb1 + 2 * BH;         // 1024*512 (yemb @ Wxe^T)

    hipMemsetAsync(barcnt, 0, 2 * 4096, stream);

    // ---- Encoder ----
    embed_kernel<<<B * SENC, 128, 0, stream>>>(xs, emb, xemb);
    gemm_nt128<<<dim3(G4 / 128, (B * SENC) / 128), 256, 0, stream>>>(
        xemb, W[0], xg, W[2], W[3], B * SENC, G4, 512, 512);
    embed_kernel<<<B * SDEC, 128, 0, stream>>>(ys, emb, yemb);
    {
        const float* xgp = xg;
        const float* whh0 = W[1];
        const float* wih1 = W[4];
        const float* whh1 = W[5];
        const float* bih1 = W[6];
        const float* bhh1 = W[7];
        float* l1o = l1out;
        float* h0b = h0buf;
        float* h1b = h1buf;
        float* hTp = hT;
        float* cTp = cT;
        unsigned* bp = barcnt;
        void* eargs[] = {(void*)&xgp, (void*)&whh0, (void*)&wih1, (void*)&whh1,
                         (void*)&bih1, (void*)&bhh1, (void*)&l1o, (void*)&h0b,
                         (void*)&h1b, (void*)&hTp, (void*)&cTp, (void*)&bp};
        hipLaunchCooperativeKernel((void*)enc_fused, dim3(NBLK), dim3(256),
                                   eargs, 0, stream);
    }

    // ---- Attention precomputes (off the recurrence) ----
    gemm_nn128<<<dim3(512 / 128, (B * SENC) / 128), 256, 0, stream>>>(
        l1out, attn_W, encT, B * SENC, 512, 512);
    gemm_nt128<<<dim3(512 / 128, (B * SDEC) / 128), 256, 0, stream>>>(
        yemb, comb_W, yg, nullptr, nullptr, B * SDEC, 512, 512, 1024);

    // ---- Decoder (single persistent kernel, 3 barriers/step) ----
    {
        const int* xs_ = xs;
        const float* enc_out_ = l1out;
        const float* encT_ = encT;
        const float* yg_ = yg;
        const float* combW_ = comb_W;
        const float* wih0 = W[8];
        const float* whh0 = W[9];
        const float* bih0 = W[10];
        const float* bhh0 = W[11];
        const float* wih1 = W[12];
        const float* whh1 = W[13];
        const float* bih1 = W[14];
        const float* bhh1 = W[15];
        const float* hT0_ = hT;
        const float* cT0_ = cT;
        const float* hT1_ = hT + BH;
        const float* cT1_ = cT + BH;
        float* dhb0_ = dhb0;
        float* dhb1_ = dhb1;
        float* inp_ = inpbuf;
        float* h2seq_ = h2seq;
        unsigned* bp = barcnt + 1024;
        void* dargs[] = {(void*)&xs_, (void*)&enc_out_, (void*)&encT_,
                         (void*)&yg_, (void*)&combW_,
                         (void*)&wih0, (void*)&whh0, (void*)&bih0, (void*)&bhh0,
                         (void*)&wih1, (void*)&whh1, (void*)&bih1, (void*)&bhh1,
                         (void*)&hT0_, (void*)&cT0_, (void*)&hT1_, (void*)&cT1_,
                         (void*)&dhb0_, (void*)&dhb1_, (void*)&inp_, (void*)&h2seq_,
                         (void*)&bp};
        hipLaunchCooperativeKernel((void*)decoder_persist, dim3(NBLK), dim3(256),
                                   dargs, 0, stream);
    }

    // ---- Output projection + argmax ----
    gemm_nt128<<<dim3(VDIM / 128, (B * SDEC) / 128), 256, 0, stream>>>(
        h2seq, emb, out + B * SDEC, nullptr, nullptr, B * SDEC, VDIM, 512, 512);
    argmax_kernel<<<B * SDEC, 256, 0, stream>>>(out + B * SDEC, out);
}

// Round 6
// 3368.633 us; speedup vs baseline: 4.2175x; 1.0754x over previous
//
#include <hip/hip_runtime.h>
#include <math.h>

// Problem constants
#define B 32
#define SENC 64
#define SDEC 32
#define HDIM 512
#define EDIM 512
#define VDIM 32000
#define G4 2048              // 4*H
#define BH (B*HDIM)          // 16384
#define NBLK 256

// ---------------------------------------------------------------------------
// Coherent (cross-XCD) accessors. sc0 sc1 = system scope (bypasses L1+L2).
// Read-only weights use normal loads -> stay L2-cached.
// ---------------------------------------------------------------------------
__device__ __forceinline__ void agent_st(float* p, float v)
{
    __hip_atomic_store(p, v, __ATOMIC_RELAXED, __HIP_MEMORY_SCOPE_AGENT);
}
// Issue-only vector coherent load: caller MUST execute
// asm volatile("s_waitcnt vmcnt(0)" ::: "memory") before using the result.
__device__ __forceinline__ float4 agent_ld4(const float* p)
{
    float4 v;
    asm volatile("global_load_dwordx4 %0, %1, off sc0 sc1"
                 : "=v"(v) : "v"(p) : "memory");
    return v;
}

// ---------------------------------------------------------------------------
// Hierarchical grid barrier (256 blocks = 8 XCD-groups x 32).
// Monotonic epochs -> no resets. vmcnt(0) drains coherent stores first.
// ---------------------------------------------------------------------------
__device__ __forceinline__ void grid_barrier_h(unsigned* bar, int xcd, unsigned ep)
{
    asm volatile("s_waitcnt vmcnt(0) lgkmcnt(0)" ::: "memory");
    __syncthreads();
    if (threadIdx.x == 0) {
        unsigned* xcnt = bar + xcd * 16;
        unsigned* gcnt = bar + 256;
        unsigned* rfl  = bar + 512 + xcd * 16;
        unsigned prev = __hip_atomic_fetch_add(xcnt, 1u, __ATOMIC_RELAXED,
                                               __HIP_MEMORY_SCOPE_AGENT);
        if (prev == ep * 32u - 1u) {
            __hip_atomic_fetch_add(gcnt, 1u, __ATOMIC_RELAXED,
                                   __HIP_MEMORY_SCOPE_AGENT);
            while (__hip_atomic_load(gcnt, __ATOMIC_RELAXED,
                                     __HIP_MEMORY_SCOPE_AGENT) < ep * 8u)
                __builtin_amdgcn_s_sleep(1);
            __hip_atomic_store(rfl, ep, __ATOMIC_RELAXED,
                               __HIP_MEMORY_SCOPE_AGENT);
        } else {
            while (__hip_atomic_load(rfl, __ATOMIC_RELAXED,
                                     __HIP_MEMORY_SCOPE_AGENT) < ep)
                __builtin_amdgcn_s_sleep(2);
        }
        asm volatile("" ::: "memory");
    }
    __syncthreads();
}

// ---------------------------------------------------------------------------
// embed: gather emb rows for a token sequence  (n_tok blocks x 128 threads)
// ---------------------------------------------------------------------------
__global__ __launch_bounds__(128) void embed_kernel(const int* __restrict__ toks,
                                                    const float* __restrict__ emb,
                                                    float* __restrict__ out)
{
    int t = blockIdx.x;
    int id = toks[t];
    const float4* src = (const float4*)(emb + (size_t)id * EDIM);
    float4* dst = (float4*)(out + (size_t)t * EDIM);
    dst[threadIdx.x] = src[threadIdx.x];   // 128 * float4 = 512 floats
}

// ---------------------------------------------------------------------------
// NT SGEMM: C[m,n] = sum_k A[m*K+k]*B[n*ldb+k] (+bias0[n]+bias1[n])
// block tile 128x128, 256 threads, 8x8 microtile.
// ---------------------------------------------------------------------------
__global__ __launch_bounds__(256) void gemm_nt128(const float* __restrict__ A,
                                                  const float* __restrict__ Bm,
                                                  float* __restrict__ C,
                                                  const float* __restrict__ bias0,
                                                  const float* __restrict__ bias1,
                                                  int M, int N, int K, int ldb)
{
    __shared__ float As[16][128];
    __shared__ float Bs[16][128];
    int tid = threadIdx.x;
    int tx = tid & 15, ty = tid >> 4;            // 16 x 16 thread grid
    int m0 = blockIdx.y * 128, n0 = blockIdx.x * 128;

    float acc[8][8];
    #pragma unroll
    for (int i = 0; i < 8; i++)
        #pragma unroll
        for (int j = 0; j < 8; j++) acc[i][j] = 0.f;

    int lr = tid >> 1, lk = (tid & 1) * 8;       // row 0..127, k 0 or 8
    const float* Aptr = A + (size_t)(m0 + lr) * K + lk;
    const float* Bptr = Bm + (size_t)(n0 + lr) * ldb + lk;

    for (int k0 = 0; k0 < K; k0 += 16) {
        float4 a1 = *(const float4*)(Aptr + k0);
        float4 a2 = *(const float4*)(Aptr + k0 + 4);
        float4 b1 = *(const float4*)(Bptr + k0);
        float4 b2 = *(const float4*)(Bptr + k0 + 4);
        As[lk + 0][lr] = a1.x; As[lk + 1][lr] = a1.y;
        As[lk + 2][lr] = a1.z; As[lk + 3][lr] = a1.w;
        As[lk + 4][lr] = a2.x; As[lk + 5][lr] = a2.y;
        As[lk + 6][lr] = a2.z; As[lk + 7][lr] = a2.w;
        Bs[lk + 0][lr] = b1.x; Bs[lk + 1][lr] = b1.y;
        Bs[lk + 2][lr] = b1.z; Bs[lk + 3][lr] = b1.w;
        Bs[lk + 4][lr] = b2.x; Bs[lk + 5][lr] = b2.y;
        Bs[lk + 6][lr] = b2.z; Bs[lk + 7][lr] = b2.w;
        __syncthreads();
        #pragma unroll
        for (int kk = 0; kk < 16; kk++) {
            float4 av1 = *(const float4*)&As[kk][ty * 8];
            float4 av2 = *(const float4*)&As[kk][ty * 8 + 4];
            float4 bv1 = *(const float4*)&Bs[kk][tx * 8];
            float4 bv2 = *(const float4*)&Bs[kk][tx * 8 + 4];
            float am[8] = {av1.x, av1.y, av1.z, av1.w, av2.x, av2.y, av2.z, av2.w};
            float bn[8] = {bv1.x, bv1.y, bv1.z, bv1.w, bv2.x, bv2.y, bv2.z, bv2.w};
            #pragma unroll
            for (int i = 0; i < 8; i++)
                #pragma unroll
                for (int j = 0; j < 8; j++)
                    acc[i][j] += am[i] * bn[j];
        }
        __syncthreads();
    }

    int nc = n0 + tx * 8;
    float bb[8];
    #pragma unroll
    for (int j = 0; j < 8; j++) {
        bb[j] = 0.f;
        if (bias0) bb[j] += bias0[nc + j];
        if (bias1) bb[j] += bias1[nc + j];
    }
    #pragma unroll
    for (int i = 0; i < 8; i++) {
        int row = m0 + ty * 8 + i;
        float4 o1 = make_float4(acc[i][0] + bb[0], acc[i][1] + bb[1],
                                acc[i][2] + bb[2], acc[i][3] + bb[3]);
        float4 o2 = make_float4(acc[i][4] + bb[4], acc[i][5] + bb[5],
                                acc[i][6] + bb[6], acc[i][7] + bb[7]);
        *(float4*)(C + (size_t)row * N + nc) = o1;
        *(float4*)(C + (size_t)row * N + nc + 4) = o2;
    }
}

// ---------------------------------------------------------------------------
// NN SGEMM: C[m,n] = sum_k A[m*K+k]*B[k*N+n]  (for encT = enc_out @ attn_W)
// ---------------------------------------------------------------------------
__global__ __launch_bounds__(256) void gemm_nn128(const float* __restrict__ A,
                                                  const float* __restrict__ Bm,
                                                  float* __restrict__ C,
                                                  int M, int N, int K)
{
    __shared__ float As[16][128];
    __shared__ float Bs[16][128];
    int tid = threadIdx.x;
    int tx = tid & 15, ty = tid >> 4;
    int m0 = blockIdx.y * 128, n0 = blockIdx.x * 128;

    float acc[8][8];
    #pragma unroll
    for (int i = 0; i < 8; i++)
        #pragma unroll
        for (int j = 0; j < 8; j++) acc[i][j] = 0.f;

    int lr = tid >> 1, lk = (tid & 1) * 8;
    const float* Aptr = A + (size_t)(m0 + lr) * K + lk;
    int bk = tid >> 5;                // 0..7
    int bn = (tid & 31) << 2;         // 0..124

    for (int k0 = 0; k0 < K; k0 += 16) {
        float4 a1 = *(const float4*)(Aptr + k0);
        float4 a2 = *(const float4*)(Aptr + k0 + 4);
        float4 v1 = *(const float4*)(Bm + (size_t)(k0 + bk) * N + n0 + bn);
        float4 v2 = *(const float4*)(Bm + (size_t)(k0 + bk + 8) * N + n0 + bn);
        As[lk + 0][lr] = a1.x; As[lk + 1][lr] = a1.y;
        As[lk + 2][lr] = a1.z; As[lk + 3][lr] = a1.w;
        As[lk + 4][lr] = a2.x; As[lk + 5][lr] = a2.y;
        As[lk + 6][lr] = a2.z; As[lk + 7][lr] = a2.w;
        *(float4*)&Bs[bk][bn] = v1;
        *(float4*)&Bs[bk + 8][bn] = v2;
        __syncthreads();
        #pragma unroll
        for (int kk = 0; kk < 16; kk++) {
            float4 av1 = *(const float4*)&As[kk][ty * 8];
            float4 av2 = *(const float4*)&As[kk][ty * 8 + 4];
            float4 bv1 = *(const float4*)&Bs[kk][tx * 8];
            float4 bv2 = *(const float4*)&Bs[kk][tx * 8 + 4];
            float am[8] = {av1.x, av1.y, av1.z, av1.w, av2.x, av2.y, av2.z, av2.w};
            float bv[8] = {bv1.x, bv1.y, bv1.z, bv1.w, bv2.x, bv2.y, bv2.z, bv2.w};
            #pragma unroll
            for (int i = 0; i < 8; i++)
                #pragma unroll
                for (int j = 0; j < 8; j++)
                    acc[i][j] += am[i] * bv[j];
        }
        __syncthreads();
    }

    int nc = n0 + tx * 8;
    #pragma unroll
    for (int i = 0; i < 8; i++) {
        int row = m0 + ty * 8 + i;
        float4 o1 = make_float4(acc[i][0], acc[i][1], acc[i][2], acc[i][3]);
        float4 o2 = make_float4(acc[i][4], acc[i][5], acc[i][6], acc[i][7]);
        *(float4*)(C + (size_t)row * N + nc) = o1;
        *(float4*)(C + (size_t)row * N + nc + 4) = o2;
    }
}

// ---------------------------------------------------------------------------
// helpers
// ---------------------------------------------------------------------------
__device__ __forceinline__ float allreduce64(float v)
{
    #pragma unroll
    for (int m = 1; m < 64; m <<= 1) v += __shfl_xor(v, m);
    return v;
}

__device__ __forceinline__ float2 lstm_update(float i_, float f_, float g_,
                                              float o_, float c)
{
    float ig = 1.f / (1.f + expf(-i_));
    float fg = 1.f / (1.f + expf(-f_));
    float gg = tanhf(g_);
    float og = 1.f / (1.f + expf(-o_));
    float cn = fg * c + ig * gg;
    float hn = og * tanhf(cn);
    return make_float2(hn, cn);
}

// ---------------------------------------------------------------------------
// Fused 2-layer encoder as a time-pipeline. 65 macro-steps, 1 barrier each.
// Blocks: xcd = blk&7, slot = blk>>3. role = slot>>4 (0: layer0, 1: layer1).
// s2 = slot&15: jgroup = xcd*8 + (s2>>1) (weights XCD-pinned), bg2 = s2&1
// (16 batch rows per block; thread handles b and b+8).
// Layer0 at step u computes t=u using precomputed xg; layer1 at u computes
// t=u-1 with Wih1@h0(t) + Whh1@h1(t-1) on the fly (no pre-gate GEMM).
// c state in registers of tid<128; h exchanged via coherent parity buffers.
// ---------------------------------------------------------------------------
__global__ __launch_bounds__(256) void enc_fused(
    const float* __restrict__ xg, const float* __restrict__ Whh0,
    const float* __restrict__ Wih1, const float* __restrict__ Whh1,
    const float* __restrict__ bih1, const float* __restrict__ bhh1,
    float* __restrict__ l1out, float* __restrict__ h0buf,
    float* __restrict__ h1buf, float* __restrict__ hT, float* __restrict__ cT,
    unsigned* __restrict__ bar)
{
    __shared__ __align__(16) float hs[16][520];
    __shared__ __align__(16) float is_[16][520];
    __shared__ float gacc[8][16][5];
    int blk = blockIdx.x;
    int xcd = blk & 7, slot = blk >> 3;
    int role = slot >> 4;
    int s2 = slot & 15;
    int jgroup = xcd * 8 + (s2 >> 1);        // [0,64)
    int bg2 = s2 & 1;
    int tid = threadIdx.x;
    int r = tid >> 3, bb = tid & 7;
    int g = r >> 3, jj = r & 7;
    int row = (g << 9) + (jgroup << 3) + jj; // gate-row in [0,2048)
    int b0 = (bg2 << 4) + bb;
    const float* w0 = role ? (Wih1 + (size_t)row * 512)
                           : (Whh0 + (size_t)row * 512);
    const float* w1 = role ? (Whh1 + (size_t)row * 512) : (const float*)0;
    float bsum = role ? (bih1[row] + bhh1[row]) : 0.f;
    float creg = 0.f;
    unsigned ep = 0;
    int p = 0;
    for (int u = 0; u <= SENC; ++u) {
        int active = role ? (u >= 1) : (u < SENC);
        int t = role ? (u - 1) : u;
        if (active) {
            // ---- stage inputs into LDS ----
            if (!role) {
                if (t == 0) {
                    float4 z = make_float4(0.f, 0.f, 0.f, 0.f);
                    #pragma unroll
                    for (int v = 0; v < 8; v++) {
                        int d = (tid + (v << 8)) << 2;
                        *(float4*)&hs[d >> 9][d & 511] = z;
                    }
                } else {
                    const float4* s4 = (const float4*)(h0buf + p * BH + ((bg2 << 4) << 9));
                    float4 hv[8];
                    #pragma unroll
                    for (int v = 0; v < 8; v++)
                        hv[v] = agent_ld4((const float*)(s4 + tid + (v << 8)));
                    asm volatile("s_waitcnt vmcnt(0)" ::: "memory");
                    #pragma unroll
                    for (int v = 0; v < 8; v++) {
                        int d = (tid + (v << 8)) << 2;
                        *(float4*)&hs[d >> 9][d & 511] = hv[v];
                    }
                }
            } else {
                const float4* s40 = (const float4*)(h0buf + p * BH + ((bg2 << 4) << 9));
                float4 hv[8];
                #pragma unroll
                for (int v = 0; v < 8; v++)
                    hv[v] = agent_ld4((const float*)(s40 + tid + (v << 8)));
                if (t == 0) {
                    asm volatile("s_waitcnt vmcnt(0)" ::: "memory");
                    float4 z = make_float4(0.f, 0.f, 0.f, 0.f);
                    #pragma unroll
                    for (int v = 0; v < 8; v++) {
                        int d = (tid + (v << 8)) << 2;
                        *(float4*)&hs[d >> 9][d & 511] = hv[v];
                        *(float4*)&is_[d >> 9][d & 511] = z;
                    }
                } else {
                    const float4* s41 = (const float4*)(h1buf + p * BH + ((bg2 << 4) << 9));
                    float4 iv[8];
                    #pragma unroll
                    for (int v = 0; v < 8; v++)
                        iv[v] = agent_ld4((const float*)(s41 + tid + (v << 8)));
                    asm volatile("s_waitcnt vmcnt(0)" ::: "memory");
                    #pragma unroll
                    for (int v = 0; v < 8; v++) {
                        int d = (tid + (v << 8)) << 2;
                        *(float4*)&hs[d >> 9][d & 511] = hv[v];
                        *(float4*)&is_[d >> 9][d & 511] = iv[v];
                    }
                }
            }
            __syncthreads();
            // ---- gates for (b0) and (b0+8) ----
            float acc0, acc1;
            if (!role) {
                acc0 = xg[(size_t)(b0 * SENC + t) * G4 + row];
                acc1 = xg[(size_t)((b0 + 8) * SENC + t) * G4 + row];
                float a00 = 0, a01 = 0, a02 = 0, a03 = 0;
                float a10 = 0, a11 = 0, a12 = 0, a13 = 0;
                const float* ha = hs[bb];
                const float* hb = hs[bb + 8];
                #pragma unroll 4
                for (int k = 0; k < 512; k += 4) {
                    float4 w = *(const float4*)(w0 + k);
                    float4 x = *(const float4*)(ha + k);
                    float4 y = *(const float4*)(hb + k);
                    a00 += w.x * x.x; a01 += w.y * x.y;
                    a02 += w.z * x.z; a03 += w.w * x.w;
                    a10 += w.x * y.x; a11 += w.y * y.y;
                    a12 += w.z * y.z; a13 += w.w * y.w;
                }
                acc0 += (a00 + a01) + (a02 + a03);
                acc1 += (a10 + a11) + (a12 + a13);
            } else {
                float a00 = 0, a01 = 0, a02 = 0, a03 = 0;
                float a10 = 0, a11 = 0, a12 = 0, a13 = 0;
                const float* h0a = hs[bb];
                const float* h0b = hs[bb + 8];
                const float* h1a = is_[bb];
                const float* h1b = is_[bb + 8];
                #pragma unroll 2
                for (int k = 0; k < 512; k += 4) {
                    float4 wi = *(const float4*)(w0 + k);
                    float4 wh = *(const float4*)(w1 + k);
                    float4 xa = *(const float4*)(h0a + k);
                    float4 xb = *(const float4*)(h0b + k);
                    float4 ya = *(const float4*)(h1a + k);
                    float4 yb = *(const float4*)(h1b + k);
                    a00 += wi.x * xa.x + wh.x * ya.x;
                    a01 += wi.y * xa.y + wh.y * ya.y;
                    a02 += wi.z * xa.z + wh.z * ya.z;
                    a03 += wi.w * xa.w + wh.w * ya.w;
                    a10 += wi.x * xb.x + wh.x * yb.x;
                    a11 += wi.y * xb.y + wh.y * yb.y;
                    a12 += wi.z * xb.z + wh.z * yb.z;
                    a13 += wi.w * xb.w + wh.w * yb.w;
                }
                acc0 = bsum + (a00 + a01) + (a02 + a03);
                acc1 = bsum + (a10 + a11) + (a12 + a13);
            }
            gacc[jj][bb][g] = acc0;
            gacc[jj][bb + 8][g] = acc1;
            __syncthreads();
            // ---- LSTM update (tid<128: one (b,jh) cell each) ----
            if (tid < 128) {
                int ujj = tid & 7, ulb = tid >> 3;    // ulb 0..15
                float g0 = gacc[ujj][ulb][0], g1 = gacc[ujj][ulb][1];
                float g2 = gacc[ujj][ulb][2], g3 = gacc[ujj][ulb][3];
                float2 hc = lstm_update(g0, g1, g2, g3, creg);
                creg = hc.y;
                int ub = (bg2 << 4) + ulb;
                int ujh = (jgroup << 3) + ujj;
                if (!role) {
                    agent_st(h0buf + (p ^ 1) * BH + ub * 512 + ujh, hc.x);
                    if (t == SENC - 1) {
                        hT[ub * 512 + ujh] = hc.x;
                        cT[ub * 512 + ujh] = hc.y;
                    }
                } else {
                    agent_st(h1buf + (p ^ 1) * BH + ub * 512 + ujh, hc.x);
                    l1out[(size_t)(ub * SENC + t) * 512 + ujh] = hc.x;
                    if (t == SENC - 1) {
                        hT[BH + ub * 512 + ujh] = hc.x;
                        cT[BH + ub * 512 + ujh] = hc.y;
                    }
                }
            }
        }
        ep++;
        grid_barrier_h(bar, xcd, ep);
        p ^= 1;
    }
}

// ---------------------------------------------------------------------------
// Decoder LSTM cell phase (device fn). Coherent x4 staging; L2 weights.
// ---------------------------------------------------------------------------
__device__ __forceinline__ void cell_phase(
    const float* __restrict__ Wih, const float* __restrict__ Whh,
    float bsum,
    const float* __restrict__ inp, const float* __restrict__ h_in,
    float* __restrict__ h_out, float* __restrict__ seqout,
    float& creg, int t, int jg, int bg, int row,
    float (*hs)[520], float (*is_)[520], float (*gacc)[8][5])
{
    int tid = threadIdx.x;
    {
        const float4* hsrc4 = (const float4*)(h_in + ((bg << 3) << 9));
        const float4* isrc4 = (const float4*)(inp + ((bg << 3) << 9));
        float4 hv4[4], iv4[4];
        #pragma unroll
        for (int u = 0; u < 4; u++) {
            hv4[u] = agent_ld4((const float*)(hsrc4 + tid + (u << 8)));
            iv4[u] = agent_ld4((const float*)(isrc4 + tid + (u << 8)));
        }
        asm volatile("s_waitcnt vmcnt(0)" ::: "memory");
        #pragma unroll
        for (int u = 0; u < 4; u++) {
            int d = (tid + (u << 8)) << 2;
            int rb = d >> 9, kk = d & 511;
            *(float4*)&hs[rb][kk] = hv4[u];
            *(float4*)&is_[rb][kk] = iv4[u];
        }
    }
    __syncthreads();
    int r = tid >> 3, bb = tid & 7;
    int g = r >> 3, jj = r & 7;
    const float* wi = Wih + (size_t)row * 512;
    const float* wh = Whh + (size_t)row * 512;
    const float* ir = is_[bb];
    const float* hr = hs[bb];
    float a0 = 0.f, a1 = 0.f, a2 = 0.f, a3 = 0.f;
    #pragma unroll 8
    for (int k = 0; k < 512; k += 4) {
        float4 wiv = *(const float4*)(wi + k);
        float4 iv = *(const float4*)(ir + k);
        float4 whv = *(const float4*)(wh + k);
        float4 hv = *(const float4*)(hr + k);
        a0 += wiv.x * iv.x + whv.x * hv.x;
        a1 += wiv.y * iv.y + whv.y * hv.y;
        a2 += wiv.z * iv.z + whv.z * hv.z;
        a3 += wiv.w * iv.w + whv.w * hv.w;
    }
    gacc[jj][bb][g] = bsum + (a0 + a1) + (a2 + a3);
    __syncthreads();
    if (tid < 64) {
        int ujj = tid & 7, ubb = tid >> 3;
        float g0 = gacc[ujj][ubb][0], g1 = gacc[ujj][ubb][1];
        float g2 = gacc[ujj][ubb][2], g3 = gacc[ujj][ubb][3];
        float2 hc = lstm_update(g0, g1, g2, g3, creg);
        creg = hc.y;
        int ub = (bg << 3) + ubb, ujh = (jg << 3) + ujj;
        agent_st(h_out + ub * 512 + ujh, hc.x);
        if (seqout) seqout[(size_t)(ub * SDEC + t) * 512 + ujh] = hc.x;
    }
}

// ---------------------------------------------------------------------------
// Persistent decoder: 32 timesteps x 3 barriers (minimum for the serial
// chain attn -> cell0 -> cell1).
// Phase A (all 256 blocks): ab = xcd*4+(slot>>3), e0 = (slot&7)*64.
//   pw[s] = h2 . encT[ab,s] (attn_W pre-applied), softmax (redundant per-b
//   across the 8 e-slice blocks, deterministic), then
//   inp[ab,e0+e] = tanh(yg[ab,t,e0+e] + sum_s aw[s]*encC[ab,s,e0+e])
//   with encC = enc_out @ comb_W[:,512:]^T precomputed -> the decoder never
//   touches enc_out or comb_W (keeps per-XCD L2 set ~3.3 MB < 4 MiB).
// Phases B/C: LSTM cells, weight rows XCD-pinned.
// ---------------------------------------------------------------------------
__global__ __launch_bounds__(256) void decoder_persist(
    const int* __restrict__ xs,
    const float* __restrict__ encT, const float* __restrict__ encC,
    const float* __restrict__ yg,
    const float* __restrict__ Wih0, const float* __restrict__ Whh0,
    const float* __restrict__ bih0, const float* __restrict__ bhh0,
    const float* __restrict__ Wih1, const float* __restrict__ Whh1,
    const float* __restrict__ bih1, const float* __restrict__ bhh1,
    const float* __restrict__ hT0, const float* __restrict__ cT0,
    const float* __restrict__ hT1, const float* __restrict__ cT1,
    float* __restrict__ dhb0, float* __restrict__ dhb1,
    float* __restrict__ inpbuf, float* __restrict__ h2seq,
    unsigned* __restrict__ bar)
{
    __shared__ __align__(16) float hs[8][520];
    __shared__ __align__(16) float is_[8][520];
    __shared__ float gacc[8][8][5];
    __shared__ __align__(16) float h2s[512];
    __shared__ float psum[4][64];
    __shared__ float pw[64];
    __shared__ float aw[64];
    int blk = blockIdx.x;
    int xcd = blk & 7, slot = blk >> 3;
    int jg = xcd * 8 + (slot >> 2), bg = slot & 3;    // cell role
    int ab = xcd * 4 + (slot >> 3);                   // attention b (XCD-pinned)
    int e0 = (slot & 7) << 6;                         // attention e-slice
    int tid = threadIdx.x;
    int lane = tid & 63, wv = tid >> 6;
    int r = tid >> 3;
    int g = r >> 3, jj = r & 7;
    int row = (g << 9) + (jg << 3) + jj;
    float bsum0 = bih0[row] + bhh0[row];
    float bsum1 = bih1[row] + bhh1[row];
    float c0 = 0.f, c1 = 0.f;
    if (tid < 64) {
        int ujj = tid & 7, ubb = tid >> 3;
        int ub = (bg << 3) + ubb, ujh = (jg << 3) + ujj;
        c0 = cT0[ub * 512 + ujh];
        c1 = cT1[ub * 512 + ujh];
    }
    unsigned ep = 0;
    int p = 0;
    for (int t = 0; t < SDEC; ++t) {
        int q = p ^ 1;
        // ---- Phase A: attention + combine ----
        {
            const float* h2p = ((t == 0) ? hT1 : dhb1 + p * BH) + ab * 512;
            if (tid < 128) {
                float4 v = agent_ld4((const float*)((const float4*)h2p + tid));
                asm volatile("s_waitcnt vmcnt(0)" ::: "memory");
                ((float4*)h2s)[tid] = v;
            }
            __syncthreads();
            // pw[s] = h2 . encT[ab,s] - neg (redundant across e-slice blocks)
            for (int s = wv; s < SENC; s += 4) {
                const float* rowp = encT + (size_t)(ab * SENC + s) * 512;
                float pp = 0.f;
                #pragma unroll
                for (int i = 0; i < 8; i++)
                    pp += h2s[lane + 64 * i] * rowp[lane + 64 * i];
                pp = allreduce64(pp);
                if (lane == 0)
                    pw[s] = pp - ((xs[ab * SENC + s] > 0) ? 0.f : 1e20f);
            }
            __syncthreads();
            if (tid < 64) {
                float v = pw[tid];
                float m = v;
                #pragma unroll
                for (int o = 1; o < 64; o <<= 1) m = fmaxf(m, __shfl_xor(m, o));
                float ex = expf(v - m);
                float sm = ex;
                #pragma unroll
                for (int o = 1; o < 64; o <<= 1) sm += __shfl_xor(sm, o);
                aw[tid] = ex / sm;
            }
            __syncthreads();
            // inp[e0+lane] = tanh(yg + sum_s aw[s]*encC[ab,s,e0+lane])
            // wave wv sums s in [wv*16, wv*16+16), coalesced 256B rows
            {
                float part = 0.f;
                const float* cb = encC + (size_t)(ab * SENC + (wv << 4)) * 512
                                + e0 + lane;
                #pragma unroll
                for (int si = 0; si < 16; si++)
                    part += aw[(wv << 4) + si] * cb[si * 512];
                psum[wv][lane] = part;
            }
            __syncthreads();
            if (tid < 64) {
                float v = psum[0][tid] + psum[1][tid] + psum[2][tid] + psum[3][tid];
                float rr = tanhf(yg[(size_t)(ab * SDEC + t) * 512 + e0 + tid] + v);
                agent_st(inpbuf + ab * 512 + e0 + tid, rr);
            }
        }
        ep++; grid_barrier_h(bar, xcd, ep);
        // ---- Phase B: layer-0 cell ----
        cell_phase(Wih0, Whh0, bsum0, inpbuf,
                   (t == 0) ? hT0 : dhb0 + p * BH, dhb0 + q * BH,
                   (float*)nullptr, c0, t, jg, bg, row, hs, is_, gacc);
        ep++; grid_barrier_h(bar, xcd, ep);
        // ---- Phase C: layer-1 cell ----
        cell_phase(Wih1, Whh1, bsum1, dhb0 + q * BH,
                   (t == 0) ? hT1 : dhb1 + p * BH, dhb1 + q * BH,
                   h2seq, c1, t, jg, bg, row, hs, is_, gacc);
        ep++; grid_barrier_h(bar, xcd, ep);
        p = q;
    }
}

// ---------------------------------------------------------------------------
// argmax over scores[m, 1:], lowest index on ties; preds[m] = index (float)
// ---------------------------------------------------------------------------
__global__ __launch_bounds__(256) void argmax_kernel(const float* __restrict__ scores,
                                                     float* __restrict__ preds)
{
    __shared__ float sv[256];
    __shared__ int si[256];
    int m = blockIdx.x;
    const float* row = scores + (size_t)m * VDIM;
    float best = -3.4e38f;
    int bi = 0x7fffffff;
    for (int v = 1 + (int)threadIdx.x; v < VDIM; v += 256) {
        float val = row[v];
        if (val > best) { best = val; bi = v; }   // ascending scan → lowest idx kept
    }
    sv[threadIdx.x] = best;
    si[threadIdx.x] = bi;
    __syncthreads();
    for (int s = 128; s > 0; s >>= 1) {
        if ((int)threadIdx.x < s) {
            float ov = sv[threadIdx.x + s];
            int oi = si[threadIdx.x + s];
            if (ov > sv[threadIdx.x] ||
                (ov == sv[threadIdx.x] && oi < si[threadIdx.x])) {
                sv[threadIdx.x] = ov;
                si[threadIdx.x] = oi;
            }
        }
        __syncthreads();
    }
    if (threadIdx.x == 0) preds[m] = (float)si[0];
}

// ---------------------------------------------------------------------------
extern "C" void kernel_launch(void* const* d_in, const int* in_sizes, int n_in,
                              void* d_out, int out_size, void* d_ws, size_t ws_size,
                              hipStream_t stream)
{
    const int* xs = (const int*)d_in[0];
    const int* ys = (const int*)d_in[1];
    const float* emb = (const float*)d_in[2];
    const float* W[16];
    for (int i = 0; i < 16; i++) W[i] = (const float*)d_in[3 + i];
    // enc layer l: W[l*4+{0:Wih,1:Whh,2:bih,3:bhh}] ; dec layer l: W[8+l*4+...]
    const float* attn_W = (const float*)d_in[19];
    const float* comb_W = (const float*)d_in[20];
    float* out = (float*)d_out;
    float* ws = (float*)d_ws;

    // workspace layout (floats)
    float* xemb   = ws;                    // 2048*512
    float* xg     = xemb + 1048576;        // 2048*2048 (layer-0 pre-gates)
    float* l1out  = xg + 4194304;          // 2048*512  (enc_out)
    float* encT   = l1out + 1048576;       // 2048*512  (enc_out @ attn_W)
    float* h0buf  = encT + 1048576;        // 2*BH
    float* h1buf  = h0buf + 2 * BH;        // 2*BH
    float* hT     = h1buf + 2 * BH;        // 2*BH (layer0 | layer1)
    float* cT     = hT + 2 * BH;           // 2*BH
    unsigned* barcnt = (unsigned*)(cT + 2 * BH);   // 2 x 1024 dwords
    // ys embeddings overlay xemb (dead after layer-0 pre-gate GEMM)
    float* yemb   = xemb;                  // 1024*512
    // decoder buffers overlay xg (dead after encoder)
    float* h2seq  = xg;                    // 1024*512
    float* inpbuf = xg + 524288;           // BH
    float* dhb0   = inpbuf + BH;           // 2*BH parity
    float* dhb1   = dhb0 + 2 * BH;         // 2*BH parity
    float* yg     = dhb1 + 2 * BH;         // 1024*512 (yemb @ Wxe^T)
    float* encC   = yg + 524288;           // 2048*512 (enc_out @ Wc^T)

    hipMemsetAsync(barcnt, 0, 2 * 4096, stream);

    // ---- Encoder ----
    embed_kernel<<<B * SENC, 128, 0, stream>>>(xs, emb, xemb);
    gemm_nt128<<<dim3(G4 / 128, (B * SENC) / 128), 256, 0, stream>>>(
        xemb, W[0], xg, W[2], W[3], B * SENC, G4, 512, 512);
    embed_kernel<<<B * SDEC, 128, 0, stream>>>(ys, emb, yemb);
    {
        const float* xgp = xg;
        const float* whh0 = W[1];
        const float* wih1 = W[4];
        const float* whh1 = W[5];
        const float* bih1 = W[6];
        const float* bhh1 = W[7];
        float* l1o = l1out;
        float* h0b = h0buf;
        float* h1b = h1buf;
        float* hTp = hT;
        float* cTp = cT;
        unsigned* bp = barcnt;
        void* eargs[] = {(void*)&xgp, (void*)&whh0, (void*)&wih1, (void*)&whh1,
                         (void*)&bih1, (void*)&bhh1, (void*)&l1o, (void*)&h0b,
                         (void*)&h1b, (void*)&hTp, (void*)&cTp, (void*)&bp};
        hipLaunchCooperativeKernel((void*)enc_fused, dim3(NBLK), dim3(256),
                                   eargs, 0, stream);
    }

    // ---- Attention precomputes (off the recurrence) ----
    gemm_nn128<<<dim3(512 / 128, (B * SENC) / 128), 256, 0, stream>>>(
        l1out, attn_W, encT, B * SENC, 512, 512);
    gemm_nt128<<<dim3(512 / 128, (B * SDEC) / 128), 256, 0, stream>>>(
        yemb, comb_W, yg, nullptr, nullptr, B * SDEC, 512, 512, 1024);
    gemm_nt128<<<dim3(512 / 128, (B * SENC) / 128), 256, 0, stream>>>(
        l1out, comb_W + 512, encC, nullptr, nullptr, B * SENC, 512, 512, 1024);

    // ---- Decoder (single persistent kernel, 3 barriers/step) ----
    {
        const int* xs_ = xs;
        const float* encT_ = encT;
        const float* encC_ = encC;
        const float* yg_ = yg;
        const float* wih0 = W[8];
        const float* whh0 = W[9];
        const float* bih0 = W[10];
        const float* bhh0 = W[11];
        const float* wih1 = W[12];
        const float* whh1 = W[13];
        const float* bih1 = W[14];
        const float* bhh1 = W[15];
        const float* hT0_ = hT;
        const float* cT0_ = cT;
        const float* hT1_ = hT + BH;
        const float* cT1_ = cT + BH;
        float* dhb0_ = dhb0;
        float* dhb1_ = dhb1;
        float* inp_ = inpbuf;
        float* h2seq_ = h2seq;
        unsigned* bp = barcnt + 1024;
        void* dargs[] = {(void*)&xs_, (void*)&encT_, (void*)&encC_,
                         (void*)&yg_,
                         (void*)&wih0, (void*)&whh0, (void*)&bih0, (void*)&bhh0,
                         (void*)&wih1, (void*)&whh1, (void*)&bih1, (void*)&bhh1,
                         (void*)&hT0_, (void*)&cT0_, (void*)&hT1_, (void*)&cT1_,
                         (void*)&dhb0_, (void*)&dhb1_, (void*)&inp_, (void*)&h2seq_,
                         (void*)&bp};
        hipLaunchCooperativeKernel((void*)decoder_persist, dim3(NBLK), dim3(256),
                                   dargs, 0, stream);
    }

    // ---- Output projection + argmax ----
    gemm_nt128<<<dim3(VDIM / 128, (B * SDEC) / 128), 256, 0, stream>>>(
        h2seq, emb, out + B * SDEC, nullptr, nullptr, B * SDEC, VDIM, 512, 512);
    argmax_kernel<<<B * SDEC, 256, 0, stream>>>(out + B * SDEC, out);
}